// Round 3
// baseline (516.569 us; speedup 1.0000x reference)
//
#include <hip/hip_runtime.h>

typedef __attribute__((ext_vector_type(4))) float f32x4;
typedef __attribute__((ext_vector_type(8))) short bf16x8;
typedef __attribute__((ext_vector_type(4))) short s16x4;
typedef unsigned short u16;

#define GLOAD_LDS16(g, l)                                                      \
  __builtin_amdgcn_global_load_lds(                                            \
      (__attribute__((address_space(1))) const void*)(g),                      \
      (__attribute__((address_space(3))) void*)(l), 16, 0, 0)

static __device__ __forceinline__ u16 f2b(float f) {
  unsigned u = __builtin_bit_cast(unsigned, f);
  unsigned r = (u + 0x7fffu + ((u >> 16) & 1u)) >> 16;
  return (u16)r;
}

static __device__ __forceinline__ f32x4 mfma16(bf16x8 a, bf16x8 b, f32x4 c) {
  return __builtin_amdgcn_mfma_f32_16x16x32_bf16(a, b, c, 0, 0, 0);
}

// ---------------- f32 -> bf16 convert ----------------
__global__ __launch_bounds__(256) void cvt_bf16(const float* __restrict__ in,
                                                u16* __restrict__ out, int n4) {
  int i = blockIdx.x * 256 + threadIdx.x;
  int stride = gridDim.x * 256;
  for (; i < n4; i += stride) {
    float4 v = ((const float4*)in)[i];
    s16x4 o;
    o[0] = (short)f2b(v.x);
    o[1] = (short)f2b(v.y);
    o[2] = (short)f2b(v.z);
    o[3] = (short)f2b(v.w);
    ((s16x4*)out)[i] = o;
  }
}

// ---------------- fused QKV GEMM (z=0:Q scaled, z=1:K, z=2:V transposed) -----
// Q is pre-scaled by log2(e)/sqrt(d_model) so attention uses exp2 directly.
#define QSCALE 0.0450842200278f
__global__ __launch_bounds__(256) void gemm_qkv3(
    const u16* __restrict__ xb, const u16* __restrict__ eb,
    const u16* __restrict__ Wqb, const u16* __restrict__ Wkb,
    const u16* __restrict__ Wvb, const float* __restrict__ bq,
    const float* __restrict__ bk, const float* __restrict__ bv,
    u16* __restrict__ Qd, u16* __restrict__ Kd, u16* __restrict__ Vtd) {
  __shared__ __align__(16) u16 As[128 * 32];
  __shared__ __align__(16) u16 Bs[128 * 32];
  const int K = 1024;
  int z = blockIdx.z;
  const u16* A = (z == 0) ? xb : eb;
  const u16* W = (z == 0) ? Wqb : (z == 1) ? Wkb : Wvb;
  const float* bias = (z == 0) ? bq : (z == 1) ? bk : bv;

  int tid = threadIdx.x;
  int w = tid >> 6, lane = tid & 63;
  int wr = w >> 1, wc = w & 1;
  int r16 = lane & 15, c4 = lane >> 4;
  int m0 = blockIdx.y * 128, n0 = blockIdx.x * 128;
  int srow = tid >> 2;
  int scol = (tid & 3) * 8;

  f32x4 acc[4][4] = {};

  const u16* ga0 = A + (size_t)(m0 + srow) * K + scol;
  const u16* gb0 = W + (size_t)(n0 + srow) * K + scol;
  char* asb = (char*)As + w * 1024;
  char* bsb = (char*)Bs + w * 1024;

  for (int k0 = 0; k0 < K; k0 += 32) {
    GLOAD_LDS16(ga0 + k0, asb);
    GLOAD_LDS16(ga0 + 64 * K + k0, asb + 4096);
    GLOAD_LDS16(gb0 + k0, bsb);
    GLOAD_LDS16(gb0 + 64 * K + k0, bsb + 4096);
    __syncthreads();
    bf16x8 af[4], bfr[4];
#pragma unroll
    for (int i = 0; i < 4; ++i)
      af[i] = *(const bf16x8*)(As + (wr * 64 + i * 16 + r16) * 32 + c4 * 8);
#pragma unroll
    for (int j = 0; j < 4; ++j)
      bfr[j] = *(const bf16x8*)(Bs + (wc * 64 + j * 16 + r16) * 32 + c4 * 8);
#pragma unroll
    for (int i = 0; i < 4; ++i)
#pragma unroll
      for (int j = 0; j < 4; ++j) acc[i][j] = mfma16(af[i], bfr[j], acc[i][j]);
    __syncthreads();
  }

  if (z < 2) {
    float oscale = (z == 0) ? QSCALE : 1.0f;
    u16* dst = (z == 0) ? Qd : Kd;
#pragma unroll
    for (int i = 0; i < 4; ++i) {
      int m = m0 + wr * 64 + i * 16 + c4 * 4;
      int b = m >> 11, s = m & 2047;
#pragma unroll
      for (int j = 0; j < 4; ++j) {
        int n = n0 + wc * 64 + j * 16 + r16;
        int h = n >> 6, d = n & 63;
        float bv = bias[n];
        u16* dp = dst + (((size_t)(b * 16 + h) * 2048 + s) * 64 + d);
#pragma unroll
        for (int r = 0; r < 4; ++r)
          dp[(size_t)r * 64] = f2b((acc[i][j][r] + bv) * oscale);
      }
    }
  } else {
    // V: write transposed, Vt[(bh*64+d)*2048 + s], 4 consecutive s per lane
#pragma unroll
    for (int i = 0; i < 4; ++i) {
      int m = m0 + wr * 64 + i * 16 + c4 * 4;
      int b = m >> 11, s = m & 2047;
#pragma unroll
      for (int j = 0; j < 4; ++j) {
        int n = n0 + wc * 64 + j * 16 + r16;
        int h = n >> 6, d = n & 63;
        float bv = bias[n];
        s16x4 o4;
#pragma unroll
        for (int r = 0; r < 4; ++r) o4[r] = (short)f2b(acc[i][j][r] + bv);
        *(s16x4*)(Vtd + ((size_t)((b * 16 + h) * 64 + d)) * 2048 + s) = o4;
      }
    }
  }
}

// ---------------- out-proj GEMM: Y = ctx * Wo^T + bo + X (f32) ----------------
__global__ __launch_bounds__(256) void gemm_out(const u16* __restrict__ A,
                                                const u16* __restrict__ W,
                                                const float* __restrict__ bias,
                                                const float* __restrict__ X,
                                                float* __restrict__ Y) {
  __shared__ __align__(16) u16 As[128 * 32];
  __shared__ __align__(16) u16 Bs[128 * 32];
  const int K = 1024;
  int tid = threadIdx.x;
  int w = tid >> 6, lane = tid & 63;
  int wr = w >> 1, wc = w & 1;
  int r16 = lane & 15, c4 = lane >> 4;
  int m0 = blockIdx.y * 128, n0 = blockIdx.x * 128;
  int srow = tid >> 2;
  int scol = (tid & 3) * 8;

  f32x4 acc[4][4] = {};

  const u16* ga0 = A + (size_t)(m0 + srow) * K + scol;
  const u16* gb0 = W + (size_t)(n0 + srow) * K + scol;
  char* asb = (char*)As + w * 1024;
  char* bsb = (char*)Bs + w * 1024;

  for (int k0 = 0; k0 < K; k0 += 32) {
    GLOAD_LDS16(ga0 + k0, asb);
    GLOAD_LDS16(ga0 + 64 * K + k0, asb + 4096);
    GLOAD_LDS16(gb0 + k0, bsb);
    GLOAD_LDS16(gb0 + 64 * K + k0, bsb + 4096);
    __syncthreads();
    bf16x8 af[4], bfr[4];
#pragma unroll
    for (int i = 0; i < 4; ++i)
      af[i] = *(const bf16x8*)(As + (wr * 64 + i * 16 + r16) * 32 + c4 * 8);
#pragma unroll
    for (int j = 0; j < 4; ++j)
      bfr[j] = *(const bf16x8*)(Bs + (wc * 64 + j * 16 + r16) * 32 + c4 * 8);
#pragma unroll
    for (int i = 0; i < 4; ++i)
#pragma unroll
      for (int j = 0; j < 4; ++j) acc[i][j] = mfma16(af[i], bfr[j], acc[i][j]);
    __syncthreads();
  }

#pragma unroll
  for (int i = 0; i < 4; ++i) {
    int m = m0 + wr * 64 + i * 16 + c4 * 4;
#pragma unroll
    for (int j = 0; j < 4; ++j) {
      int n = n0 + wc * 64 + j * 16 + r16;
      float bv = bias[n];
#pragma unroll
      for (int r = 0; r < 4; ++r) {
        size_t idx = (size_t)(m + r) * 1024 + n;
        Y[idx] = acc[i][j][r] + bv + X[idx];
      }
    }
  }
}

// ---------------- fused attention v3: 16 q rows/wave, 16 waves/CU ------------
// S^T = mfma(K, Q); permuted K-row map makes the PV A-fragment lane-local.
// Q pre-scaled by log2e/32 -> P = exp2(S); normalizer folded into exponent.
__global__ __launch_bounds__(256, 4) void attn_k(const u16* __restrict__ Q,
                                                 const u16* __restrict__ Kg,
                                                 const u16* __restrict__ Vt,
                                                 float* __restrict__ attnw,
                                                 u16* __restrict__ ctx) {
  int tid = threadIdx.x;
  int w = tid >> 6, lane = tid & 63;
  int r16 = lane & 15, c4 = lane >> 4;
  int bh = blockIdx.y;
  int b = bh >> 4, h = bh & 15;
  int q0 = blockIdx.x * 64 + w * 16;

  const u16* Qp = Q + ((size_t)bh * 2048 + q0) * 64;
  const u16* Kp = Kg + (size_t)bh * 2048 * 64;
  const u16* Vp = Vt + (size_t)bh * 64 * 2048;

  bf16x8 qf0 = *(const bf16x8*)(Qp + (size_t)r16 * 64 + c4 * 8);
  bf16x8 qf1 = *(const bf16x8*)(Qp + (size_t)r16 * 64 + 32 + c4 * 8);

  // permuted K row base: tile0 row = (r16>>2)*8 + (r16&3); tile1 = +4 rows
  const u16* kbase = Kp + (size_t)((r16 >> 2) * 8 + (r16 & 3)) * 64 + c4 * 8;

  // ---------------- pass 1: row sums of exp2(S) ----------------
  float sum = 0.f;
  {
    bf16x8 k00 = *(const bf16x8*)(kbase);
    bf16x8 k01 = *(const bf16x8*)(kbase + 32);
    bf16x8 k10 = *(const bf16x8*)(kbase + 256);
    bf16x8 k11 = *(const bf16x8*)(kbase + 288);
    for (int kv0 = 0; kv0 < 2048; kv0 += 32) {
      int nxt = (kv0 + 32) & 2047;
      const u16* kpn = kbase + (size_t)nxt * 64;
      bf16x8 n00 = *(const bf16x8*)(kpn);
      bf16x8 n01 = *(const bf16x8*)(kpn + 32);
      bf16x8 n10 = *(const bf16x8*)(kpn + 256);
      bf16x8 n11 = *(const bf16x8*)(kpn + 288);
      f32x4 s0 = {}, s1 = {};
      __builtin_amdgcn_s_setprio(1);
      s0 = mfma16(k00, qf0, s0);
      s0 = mfma16(k01, qf1, s0);
      s1 = mfma16(k10, qf0, s1);
      s1 = mfma16(k11, qf1, s1);
      __builtin_amdgcn_s_setprio(0);
#pragma unroll
      for (int r = 0; r < 4; ++r)
        sum += __builtin_amdgcn_exp2f(s0[r]) + __builtin_amdgcn_exp2f(s1[r]);
      k00 = n00; k01 = n01; k10 = n10; k11 = n11;
    }
  }
  sum += __shfl_xor(sum, 16, 64);
  sum += __shfl_xor(sum, 32, 64);
  float nls = -__log2f(sum);

  // ---------------- pass 2: P write + ctx = P*V ----------------
  f32x4 o[4] = {};
  float* ap = attnw + ((size_t)bh * 2048 + q0 + r16) * 2048;
  {
    bf16x8 k00 = *(const bf16x8*)(kbase);
    bf16x8 k01 = *(const bf16x8*)(kbase + 32);
    bf16x8 k10 = *(const bf16x8*)(kbase + 256);
    bf16x8 k11 = *(const bf16x8*)(kbase + 288);
    for (int kv0 = 0; kv0 < 2048; kv0 += 32) {
      int nxt = (kv0 + 32) & 2047;
      const u16* kpn = kbase + (size_t)nxt * 64;
      bf16x8 n00 = *(const bf16x8*)(kpn);
      bf16x8 n01 = *(const bf16x8*)(kpn + 32);
      bf16x8 n10 = *(const bf16x8*)(kpn + 256);
      bf16x8 n11 = *(const bf16x8*)(kpn + 288);
      bf16x8 v0 = *(const bf16x8*)(Vp + (size_t)(0 * 16 + r16) * 2048 + kv0 + c4 * 8);
      bf16x8 v1 = *(const bf16x8*)(Vp + (size_t)(1 * 16 + r16) * 2048 + kv0 + c4 * 8);
      bf16x8 v2 = *(const bf16x8*)(Vp + (size_t)(2 * 16 + r16) * 2048 + kv0 + c4 * 8);
      bf16x8 v3 = *(const bf16x8*)(Vp + (size_t)(3 * 16 + r16) * 2048 + kv0 + c4 * 8);
      f32x4 s0 = {}, s1 = {};
      __builtin_amdgcn_s_setprio(1);
      s0 = mfma16(k00, qf0, s0);
      s0 = mfma16(k01, qf1, s0);
      s1 = mfma16(k10, qf0, s1);
      s1 = mfma16(k11, qf1, s1);
      __builtin_amdgcn_s_setprio(0);
      f32x4 p0, p1;
#pragma unroll
      for (int r = 0; r < 4; ++r) {
        p0[r] = __builtin_amdgcn_exp2f(s0[r] + nls);
        p1[r] = __builtin_amdgcn_exp2f(s1[r] + nls);
      }
      *(f32x4*)(ap + kv0 + c4 * 8) = p0;
      *(f32x4*)(ap + kv0 + c4 * 8 + 4) = p1;
      bf16x8 pf;
#pragma unroll
      for (int r = 0; r < 4; ++r) {
        pf[r] = (short)f2b(p0[r]);
        pf[r + 4] = (short)f2b(p1[r]);
      }
      __builtin_amdgcn_s_setprio(1);
      o[0] = mfma16(pf, v0, o[0]);
      o[1] = mfma16(pf, v1, o[1]);
      o[2] = mfma16(pf, v2, o[2]);
      o[3] = mfma16(pf, v3, o[3]);
      __builtin_amdgcn_s_setprio(0);
      k00 = n00; k01 = n01; k10 = n10; k11 = n11;
    }
  }

#pragma unroll
  for (int dt = 0; dt < 4; ++dt)
#pragma unroll
    for (int r = 0; r < 4; ++r)
      ctx[((size_t)(b * 2048 + q0 + c4 * 4 + r)) * 1024 + h * 64 + dt * 16 +
          r16] = f2b(o[dt][r]);
}

// ---------------- LayerNorm over last dim (1024), wave per row ----------------
__global__ __launch_bounds__(256) void ln_k(const float* __restrict__ Y,
                                            const float* __restrict__ gamma,
                                            const float* __restrict__ beta,
                                            float* __restrict__ out) {
  int row = blockIdx.x * 4 + (threadIdx.x >> 6);
  int lane = threadIdx.x & 63;
  const float* yr = Y + (size_t)row * 1024;
  float4 v[4];
  float sum = 0.f, sq = 0.f;
#pragma unroll
  for (int i = 0; i < 4; ++i) {
    v[i] = *(const float4*)(yr + i * 256 + lane * 4);
    sum += v[i].x + v[i].y + v[i].z + v[i].w;
    sq += v[i].x * v[i].x + v[i].y * v[i].y + v[i].z * v[i].z + v[i].w * v[i].w;
  }
#pragma unroll
  for (int m = 1; m < 64; m <<= 1) {
    sum += __shfl_xor(sum, m, 64);
    sq += __shfl_xor(sq, m, 64);
  }
  float mu = sum * (1.f / 1024.f);
  float var = sq * (1.f / 1024.f) - mu * mu;
  float rs = rsqrtf(var + 1e-5f);
  float* orow = out + (size_t)row * 1024;
#pragma unroll
  for (int i = 0; i < 4; ++i) {
    int c = i * 256 + lane * 4;
    float4 g = *(const float4*)(gamma + c);
    float4 be = *(const float4*)(beta + c);
    float4 o;
    o.x = (v[i].x - mu) * rs * g.x + be.x;
    o.y = (v[i].y - mu) * rs * g.y + be.y;
    o.z = (v[i].z - mu) * rs * g.z + be.z;
    o.w = (v[i].w - mu) * rs * g.w + be.w;
    *(float4*)(orow + c) = o;
  }
}

extern "C" void kernel_launch(void* const* d_in, const int* in_sizes, int n_in,
                              void* d_out, int out_size, void* d_ws,
                              size_t ws_size, hipStream_t stream) {
  const float* x = (const float*)d_in[0];
  const float* enc = (const float*)d_in[1];
  const float* Wq = (const float*)d_in[2];
  const float* bq = (const float*)d_in[3];
  const float* Wk = (const float*)d_in[4];
  const float* bk = (const float*)d_in[5];
  const float* Wv = (const float*)d_in[6];
  const float* bv = (const float*)d_in[7];
  const float* Wo = (const float*)d_in[8];
  const float* bo = (const float*)d_in[9];
  const float* gamma = (const float*)d_in[10];
  const float* beta = (const float*)d_in[11];

  float* out = (float*)d_out;
  float* attnw = out + (size_t)4194304;  // 2*2048*1024

  char* ws = (char*)d_ws;
  u16* xb = (u16*)(ws + (size_t)0);
  u16* eb = (u16*)(ws + ((size_t)8 << 20));
  u16* Wqb = (u16*)(ws + ((size_t)16 << 20));
  u16* Wkb = (u16*)(ws + ((size_t)18 << 20));
  u16* Wvb = (u16*)(ws + ((size_t)20 << 20));
  u16* Wob = (u16*)(ws + ((size_t)22 << 20));
  u16* Qws = (u16*)(ws + ((size_t)24 << 20));
  u16* Kws = (u16*)(ws + ((size_t)32 << 20));
  u16* Vt = (u16*)(ws + ((size_t)48 << 20));
  u16* ctx = (u16*)(ws + ((size_t)40 << 20));
  float* Yws = (float*)(ws + (size_t)0);  // reuse xb/eb (dead after gemms)

  cvt_bf16<<<dim3(1024), 256, 0, stream>>>(x, xb, 1048576);
  cvt_bf16<<<dim3(1024), 256, 0, stream>>>(enc, eb, 1048576);
  cvt_bf16<<<dim3(256), 256, 0, stream>>>(Wq, Wqb, 262144);
  cvt_bf16<<<dim3(256), 256, 0, stream>>>(Wk, Wkb, 262144);
  cvt_bf16<<<dim3(256), 256, 0, stream>>>(Wv, Wvb, 262144);
  cvt_bf16<<<dim3(256), 256, 0, stream>>>(Wo, Wob, 262144);

  gemm_qkv3<<<dim3(8, 32, 3), 256, 0, stream>>>(xb, eb, Wqb, Wkb, Wvb, bq, bk,
                                                bv, Qws, Kws, Vt);

  attn_k<<<dim3(32, 32), 256, 0, stream>>>(Qws, Kws, Vt, attnw, ctx);

  gemm_out<<<dim3(8, 32), 256, 0, stream>>>(ctx, Wob, bo, x, Yws);

  ln_k<<<dim3(1024), 256, 0, stream>>>(Yws, gamma, beta, out);
}

// Round 4
// 511.517 us; speedup vs baseline: 1.0099x; 1.0099x over previous
//
#include <hip/hip_runtime.h>

typedef __attribute__((ext_vector_type(4))) float f32x4;
typedef __attribute__((ext_vector_type(8))) short bf16x8;
typedef __attribute__((ext_vector_type(4))) short s16x4;
typedef unsigned short u16;

#define GLOAD_LDS16(g, l)                                                      \
  __builtin_amdgcn_global_load_lds(                                            \
      (__attribute__((address_space(1))) const void*)(g),                      \
      (__attribute__((address_space(3))) void*)(l), 16, 0, 0)

static __device__ __forceinline__ u16 f2b(float f) {
  unsigned u = __builtin_bit_cast(unsigned, f);
  unsigned r = (u + 0x7fffu + ((u >> 16) & 1u)) >> 16;
  return (u16)r;
}

static __device__ __forceinline__ f32x4 mfma16(bf16x8 a, bf16x8 b, f32x4 c) {
  return __builtin_amdgcn_mfma_f32_16x16x32_bf16(a, b, c, 0, 0, 0);
}

// ---------------- f32 -> bf16 convert ----------------
__global__ __launch_bounds__(256) void cvt_bf16(const float* __restrict__ in,
                                                u16* __restrict__ out, int n4) {
  int i = blockIdx.x * 256 + threadIdx.x;
  int stride = gridDim.x * 256;
  for (; i < n4; i += stride) {
    float4 v = ((const float4*)in)[i];
    s16x4 o;
    o[0] = (short)f2b(v.x);
    o[1] = (short)f2b(v.y);
    o[2] = (short)f2b(v.z);
    o[3] = (short)f2b(v.w);
    ((s16x4*)out)[i] = o;
  }
}

// ---------------- fused QKV GEMM (z=0:Q scaled, z=1:K, z=2:V transposed) -----
// Q is pre-scaled by log2(e)/sqrt(d_model) so attention uses exp2 directly.
#define QSCALE 0.0450842200278f
__global__ __launch_bounds__(256) void gemm_qkv3(
    const u16* __restrict__ xb, const u16* __restrict__ eb,
    const u16* __restrict__ Wqb, const u16* __restrict__ Wkb,
    const u16* __restrict__ Wvb, const float* __restrict__ bq,
    const float* __restrict__ bk, const float* __restrict__ bv,
    u16* __restrict__ Qd, u16* __restrict__ Kd, u16* __restrict__ Vtd) {
  __shared__ __align__(16) u16 As[128 * 32];
  __shared__ __align__(16) u16 Bs[128 * 32];
  const int K = 1024;
  int z = blockIdx.z;
  const u16* A = (z == 0) ? xb : eb;
  const u16* W = (z == 0) ? Wqb : (z == 1) ? Wkb : Wvb;
  const float* bias = (z == 0) ? bq : (z == 1) ? bk : bv;

  int tid = threadIdx.x;
  int w = tid >> 6, lane = tid & 63;
  int wr = w >> 1, wc = w & 1;
  int r16 = lane & 15, c4 = lane >> 4;
  int m0 = blockIdx.y * 128, n0 = blockIdx.x * 128;
  int srow = tid >> 2;
  int scol = (tid & 3) * 8;

  f32x4 acc[4][4] = {};

  const u16* ga0 = A + (size_t)(m0 + srow) * K + scol;
  const u16* gb0 = W + (size_t)(n0 + srow) * K + scol;
  char* asb = (char*)As + w * 1024;
  char* bsb = (char*)Bs + w * 1024;

  for (int k0 = 0; k0 < K; k0 += 32) {
    GLOAD_LDS16(ga0 + k0, asb);
    GLOAD_LDS16(ga0 + 64 * K + k0, asb + 4096);
    GLOAD_LDS16(gb0 + k0, bsb);
    GLOAD_LDS16(gb0 + 64 * K + k0, bsb + 4096);
    __syncthreads();
    bf16x8 af[4], bfr[4];
#pragma unroll
    for (int i = 0; i < 4; ++i)
      af[i] = *(const bf16x8*)(As + (wr * 64 + i * 16 + r16) * 32 + c4 * 8);
#pragma unroll
    for (int j = 0; j < 4; ++j)
      bfr[j] = *(const bf16x8*)(Bs + (wc * 64 + j * 16 + r16) * 32 + c4 * 8);
#pragma unroll
    for (int i = 0; i < 4; ++i)
#pragma unroll
      for (int j = 0; j < 4; ++j) acc[i][j] = mfma16(af[i], bfr[j], acc[i][j]);
    __syncthreads();
  }

  if (z < 2) {
    float oscale = (z == 0) ? QSCALE : 1.0f;
    u16* dst = (z == 0) ? Qd : Kd;
#pragma unroll
    for (int i = 0; i < 4; ++i) {
      int m = m0 + wr * 64 + i * 16 + c4 * 4;
      int b = m >> 11, s = m & 2047;
#pragma unroll
      for (int j = 0; j < 4; ++j) {
        int n = n0 + wc * 64 + j * 16 + r16;
        int h = n >> 6, d = n & 63;
        float bv = bias[n];
        u16* dp = dst + (((size_t)(b * 16 + h) * 2048 + s) * 64 + d);
#pragma unroll
        for (int r = 0; r < 4; ++r)
          dp[(size_t)r * 64] = f2b((acc[i][j][r] + bv) * oscale);
      }
    }
  } else {
    // V: write transposed, Vt[(bh*64+d)*2048 + s], 4 consecutive s per lane
#pragma unroll
    for (int i = 0; i < 4; ++i) {
      int m = m0 + wr * 64 + i * 16 + c4 * 4;
      int b = m >> 11, s = m & 2047;
#pragma unroll
      for (int j = 0; j < 4; ++j) {
        int n = n0 + wc * 64 + j * 16 + r16;
        int h = n >> 6, d = n & 63;
        float bv = bias[n];
        s16x4 o4;
#pragma unroll
        for (int r = 0; r < 4; ++r) o4[r] = (short)f2b(acc[i][j][r] + bv);
        *(s16x4*)(Vtd + ((size_t)((b * 16 + h) * 64 + d)) * 2048 + s) = o4;
      }
    }
  }
}

// ---------------- out-proj GEMM: Y = ctx * Wo^T + bo + X (f32) ----------------
__global__ __launch_bounds__(256) void gemm_out(const u16* __restrict__ A,
                                                const u16* __restrict__ W,
                                                const float* __restrict__ bias,
                                                const float* __restrict__ X,
                                                float* __restrict__ Y) {
  __shared__ __align__(16) u16 As[128 * 32];
  __shared__ __align__(16) u16 Bs[128 * 32];
  const int K = 1024;
  int tid = threadIdx.x;
  int w = tid >> 6, lane = tid & 63;
  int wr = w >> 1, wc = w & 1;
  int r16 = lane & 15, c4 = lane >> 4;
  int m0 = blockIdx.y * 128, n0 = blockIdx.x * 128;
  int srow = tid >> 2;
  int scol = (tid & 3) * 8;

  f32x4 acc[4][4] = {};

  const u16* ga0 = A + (size_t)(m0 + srow) * K + scol;
  const u16* gb0 = W + (size_t)(n0 + srow) * K + scol;
  char* asb = (char*)As + w * 1024;
  char* bsb = (char*)Bs + w * 1024;

  for (int k0 = 0; k0 < K; k0 += 32) {
    GLOAD_LDS16(ga0 + k0, asb);
    GLOAD_LDS16(ga0 + 64 * K + k0, asb + 4096);
    GLOAD_LDS16(gb0 + k0, bsb);
    GLOAD_LDS16(gb0 + 64 * K + k0, bsb + 4096);
    __syncthreads();
    bf16x8 af[4], bfr[4];
#pragma unroll
    for (int i = 0; i < 4; ++i)
      af[i] = *(const bf16x8*)(As + (wr * 64 + i * 16 + r16) * 32 + c4 * 8);
#pragma unroll
    for (int j = 0; j < 4; ++j)
      bfr[j] = *(const bf16x8*)(Bs + (wc * 64 + j * 16 + r16) * 32 + c4 * 8);
#pragma unroll
    for (int i = 0; i < 4; ++i)
#pragma unroll
      for (int j = 0; j < 4; ++j) acc[i][j] = mfma16(af[i], bfr[j], acc[i][j]);
    __syncthreads();
  }

#pragma unroll
  for (int i = 0; i < 4; ++i) {
    int m = m0 + wr * 64 + i * 16 + c4 * 4;
#pragma unroll
    for (int j = 0; j < 4; ++j) {
      int n = n0 + wc * 64 + j * 16 + r16;
      float bv = bias[n];
#pragma unroll
      for (int r = 0; r < 4; ++r) {
        size_t idx = (size_t)(m + r) * 1024 + n;
        Y[idx] = acc[i][j][r] + bv + X[idx];
      }
    }
  }
}

// ---------------- fused attention v4 ----------------
// 1D grid, id = qt*32 + bh  ->  XCD(id%8) = bh%8: all q-tiles of one bh share
// one XCD's L2 (4 bh x 512KB = 2MB resident). attnw written with NONTEMPORAL
// stores so the 533MB P stream doesn't evict K/V from L2.
// S^T = mfma(K, Q); permuted K-row map makes the PV A-fragment lane-local.
// Q pre-scaled by log2e/32 -> P = exp2(S); normalizer folded into exponent.
__global__ __launch_bounds__(256, 4) void attn_k(const u16* __restrict__ Q,
                                                 const u16* __restrict__ Kg,
                                                 const u16* __restrict__ Vt,
                                                 float* __restrict__ attnw,
                                                 u16* __restrict__ ctx) {
  int tid = threadIdx.x;
  int w = tid >> 6, lane = tid & 63;
  int r16 = lane & 15, c4 = lane >> 4;
  int id = blockIdx.x;
  int bh = id & 31, qt = id >> 5;
  int b = bh >> 4, h = bh & 15;
  int q0 = qt * 64 + w * 16;

  const u16* Qp = Q + ((size_t)bh * 2048 + q0) * 64;
  const u16* Kp = Kg + (size_t)bh * 2048 * 64;
  const u16* Vp = Vt + (size_t)bh * 64 * 2048;

  bf16x8 qf0 = *(const bf16x8*)(Qp + (size_t)r16 * 64 + c4 * 8);
  bf16x8 qf1 = *(const bf16x8*)(Qp + (size_t)r16 * 64 + 32 + c4 * 8);

  // permuted K row base: tile0 row = (r16>>2)*8 + (r16&3); tile1 = +4 rows
  const u16* kbase = Kp + (size_t)((r16 >> 2) * 8 + (r16 & 3)) * 64 + c4 * 8;

  // ---------------- pass 1: row sums of exp2(S) ----------------
  float sum = 0.f;
  {
    bf16x8 k00 = *(const bf16x8*)(kbase);
    bf16x8 k01 = *(const bf16x8*)(kbase + 32);
    bf16x8 k10 = *(const bf16x8*)(kbase + 256);
    bf16x8 k11 = *(const bf16x8*)(kbase + 288);
    for (int kv0 = 0; kv0 < 2048; kv0 += 32) {
      int nxt = (kv0 + 32) & 2047;
      const u16* kpn = kbase + (size_t)nxt * 64;
      bf16x8 n00 = *(const bf16x8*)(kpn);
      bf16x8 n01 = *(const bf16x8*)(kpn + 32);
      bf16x8 n10 = *(const bf16x8*)(kpn + 256);
      bf16x8 n11 = *(const bf16x8*)(kpn + 288);
      f32x4 s0 = {}, s1 = {};
      __builtin_amdgcn_s_setprio(1);
      s0 = mfma16(k00, qf0, s0);
      s0 = mfma16(k01, qf1, s0);
      s1 = mfma16(k10, qf0, s1);
      s1 = mfma16(k11, qf1, s1);
      __builtin_amdgcn_s_setprio(0);
#pragma unroll
      for (int r = 0; r < 4; ++r)
        sum += __builtin_amdgcn_exp2f(s0[r]) + __builtin_amdgcn_exp2f(s1[r]);
      k00 = n00; k01 = n01; k10 = n10; k11 = n11;
    }
  }
  sum += __shfl_xor(sum, 16, 64);
  sum += __shfl_xor(sum, 32, 64);
  float nls = -__log2f(sum);

  // ---------------- pass 2: P write (nontemporal) + ctx = P*V ----------------
  f32x4 o[4] = {};
  float* ap = attnw + ((size_t)bh * 2048 + q0 + r16) * 2048;
  {
    bf16x8 k00 = *(const bf16x8*)(kbase);
    bf16x8 k01 = *(const bf16x8*)(kbase + 32);
    bf16x8 k10 = *(const bf16x8*)(kbase + 256);
    bf16x8 k11 = *(const bf16x8*)(kbase + 288);
    for (int kv0 = 0; kv0 < 2048; kv0 += 32) {
      int nxt = (kv0 + 32) & 2047;
      const u16* kpn = kbase + (size_t)nxt * 64;
      bf16x8 n00 = *(const bf16x8*)(kpn);
      bf16x8 n01 = *(const bf16x8*)(kpn + 32);
      bf16x8 n10 = *(const bf16x8*)(kpn + 256);
      bf16x8 n11 = *(const bf16x8*)(kpn + 288);
      bf16x8 v0 = *(const bf16x8*)(Vp + (size_t)(0 * 16 + r16) * 2048 + kv0 + c4 * 8);
      bf16x8 v1 = *(const bf16x8*)(Vp + (size_t)(1 * 16 + r16) * 2048 + kv0 + c4 * 8);
      bf16x8 v2 = *(const bf16x8*)(Vp + (size_t)(2 * 16 + r16) * 2048 + kv0 + c4 * 8);
      bf16x8 v3 = *(const bf16x8*)(Vp + (size_t)(3 * 16 + r16) * 2048 + kv0 + c4 * 8);
      f32x4 s0 = {}, s1 = {};
      __builtin_amdgcn_s_setprio(1);
      s0 = mfma16(k00, qf0, s0);
      s0 = mfma16(k01, qf1, s0);
      s1 = mfma16(k10, qf0, s1);
      s1 = mfma16(k11, qf1, s1);
      __builtin_amdgcn_s_setprio(0);
      f32x4 p0, p1;
#pragma unroll
      for (int r = 0; r < 4; ++r) {
        p0[r] = __builtin_amdgcn_exp2f(s0[r] + nls);
        p1[r] = __builtin_amdgcn_exp2f(s1[r] + nls);
      }
      __builtin_nontemporal_store(p0, (f32x4*)(ap + kv0 + c4 * 8));
      __builtin_nontemporal_store(p1, (f32x4*)(ap + kv0 + c4 * 8 + 4));
      bf16x8 pf;
#pragma unroll
      for (int r = 0; r < 4; ++r) {
        pf[r] = (short)f2b(p0[r]);
        pf[r + 4] = (short)f2b(p1[r]);
      }
      __builtin_amdgcn_s_setprio(1);
      o[0] = mfma16(pf, v0, o[0]);
      o[1] = mfma16(pf, v1, o[1]);
      o[2] = mfma16(pf, v2, o[2]);
      o[3] = mfma16(pf, v3, o[3]);
      __builtin_amdgcn_s_setprio(0);
      k00 = n00; k01 = n01; k10 = n10; k11 = n11;
    }
  }

#pragma unroll
  for (int dt = 0; dt < 4; ++dt)
#pragma unroll
    for (int r = 0; r < 4; ++r)
      ctx[((size_t)(b * 2048 + q0 + c4 * 4 + r)) * 1024 + h * 64 + dt * 16 +
          r16] = f2b(o[dt][r]);
}

// ---------------- LayerNorm over last dim (1024), wave per row ----------------
__global__ __launch_bounds__(256) void ln_k(const float* __restrict__ Y,
                                            const float* __restrict__ gamma,
                                            const float* __restrict__ beta,
                                            float* __restrict__ out) {
  int row = blockIdx.x * 4 + (threadIdx.x >> 6);
  int lane = threadIdx.x & 63;
  const float* yr = Y + (size_t)row * 1024;
  float4 v[4];
  float sum = 0.f, sq = 0.f;
#pragma unroll
  for (int i = 0; i < 4; ++i) {
    v[i] = *(const float4*)(yr + i * 256 + lane * 4);
    sum += v[i].x + v[i].y + v[i].z + v[i].w;
    sq += v[i].x * v[i].x + v[i].y * v[i].y + v[i].z * v[i].z + v[i].w * v[i].w;
  }
#pragma unroll
  for (int m = 1; m < 64; m <<= 1) {
    sum += __shfl_xor(sum, m, 64);
    sq += __shfl_xor(sq, m, 64);
  }
  float mu = sum * (1.f / 1024.f);
  float var = sq * (1.f / 1024.f) - mu * mu;
  float rs = rsqrtf(var + 1e-5f);
  float* orow = out + (size_t)row * 1024;
#pragma unroll
  for (int i = 0; i < 4; ++i) {
    int c = i * 256 + lane * 4;
    float4 g = *(const float4*)(gamma + c);
    float4 be = *(const float4*)(beta + c);
    float4 o;
    o.x = (v[i].x - mu) * rs * g.x + be.x;
    o.y = (v[i].y - mu) * rs * g.y + be.y;
    o.z = (v[i].z - mu) * rs * g.z + be.z;
    o.w = (v[i].w - mu) * rs * g.w + be.w;
    *(float4*)(orow + c) = o;
  }
}

extern "C" void kernel_launch(void* const* d_in, const int* in_sizes, int n_in,
                              void* d_out, int out_size, void* d_ws,
                              size_t ws_size, hipStream_t stream) {
  const float* x = (const float*)d_in[0];
  const float* enc = (const float*)d_in[1];
  const float* Wq = (const float*)d_in[2];
  const float* bq = (const float*)d_in[3];
  const float* Wk = (const float*)d_in[4];
  const float* bk = (const float*)d_in[5];
  const float* Wv = (const float*)d_in[6];
  const float* bv = (const float*)d_in[7];
  const float* Wo = (const float*)d_in[8];
  const float* bo = (const float*)d_in[9];
  const float* gamma = (const float*)d_in[10];
  const float* beta = (const float*)d_in[11];

  float* out = (float*)d_out;
  float* attnw = out + (size_t)4194304;  // 2*2048*1024

  char* ws = (char*)d_ws;
  u16* xb = (u16*)(ws + (size_t)0);
  u16* eb = (u16*)(ws + ((size_t)8 << 20));
  u16* Wqb = (u16*)(ws + ((size_t)16 << 20));
  u16* Wkb = (u16*)(ws + ((size_t)18 << 20));
  u16* Wvb = (u16*)(ws + ((size_t)20 << 20));
  u16* Wob = (u16*)(ws + ((size_t)22 << 20));
  u16* Qws = (u16*)(ws + ((size_t)24 << 20));
  u16* Kws = (u16*)(ws + ((size_t)32 << 20));
  u16* Vt = (u16*)(ws + ((size_t)48 << 20));
  u16* ctx = (u16*)(ws + ((size_t)40 << 20));
  float* Yws = (float*)(ws + (size_t)0);  // reuse xb/eb (dead after gemms)

  cvt_bf16<<<dim3(1024), 256, 0, stream>>>(x, xb, 1048576);
  cvt_bf16<<<dim3(1024), 256, 0, stream>>>(enc, eb, 1048576);
  cvt_bf16<<<dim3(256), 256, 0, stream>>>(Wq, Wqb, 262144);
  cvt_bf16<<<dim3(256), 256, 0, stream>>>(Wk, Wkb, 262144);
  cvt_bf16<<<dim3(256), 256, 0, stream>>>(Wv, Wvb, 262144);
  cvt_bf16<<<dim3(256), 256, 0, stream>>>(Wo, Wob, 262144);

  gemm_qkv3<<<dim3(8, 32, 3), 256, 0, stream>>>(xb, eb, Wqb, Wkb, Wvb, bq, bk,
                                                bv, Qws, Kws, Vt);

  attn_k<<<dim3(1024), 256, 0, stream>>>(Qws, Kws, Vt, attnw, ctx);

  gemm_out<<<dim3(8, 32), 256, 0, stream>>>(ctx, Wob, bo, x, Yws);

  ln_k<<<dim3(1024), 256, 0, stream>>>(Yws, gamma, beta, out);
}

// Round 5
// 310.826 us; speedup vs baseline: 1.6619x; 1.6457x over previous
//
#include <hip/hip_runtime.h>

typedef __attribute__((ext_vector_type(4))) float f32x4;
typedef __attribute__((ext_vector_type(8))) short bf16x8;
typedef __attribute__((ext_vector_type(4))) short s16x4;
typedef unsigned short u16;

#define GLOAD_LDS16(g, l)                                                      \
  __builtin_amdgcn_global_load_lds(                                            \
      (__attribute__((address_space(1))) const void*)(g),                      \
      (__attribute__((address_space(3))) void*)(l), 16, 0, 0)

static __device__ __forceinline__ u16 f2b(float f) {
  unsigned u = __builtin_bit_cast(unsigned, f);
  unsigned r = (u + 0x7fffu + ((u >> 16) & 1u)) >> 16;
  return (u16)r;
}

static __device__ __forceinline__ f32x4 mfma16(bf16x8 a, bf16x8 b, f32x4 c) {
  return __builtin_amdgcn_mfma_f32_16x16x32_bf16(a, b, c, 0, 0, 0);
}

// bank swizzle: chunk' = chunk ^ fsw(row); fsw spreads the 8 16B-chunks of a
// 128B row across rows so MFMA-fragment reads are 2-way (free) not 16-way.
static __device__ __forceinline__ int fsw(int row) {
  return (row & 7) ^ ((row & 8) >> 1);
}

// ---------------- f32 -> bf16 convert ----------------
__global__ __launch_bounds__(256) void cvt_bf16(const float* __restrict__ in,
                                                u16* __restrict__ out, int n4) {
  int i = blockIdx.x * 256 + threadIdx.x;
  int stride = gridDim.x * 256;
  for (; i < n4; i += stride) {
    float4 v = ((const float4*)in)[i];
    s16x4 o;
    o[0] = (short)f2b(v.x);
    o[1] = (short)f2b(v.y);
    o[2] = (short)f2b(v.z);
    o[3] = (short)f2b(v.w);
    ((s16x4*)out)[i] = o;
  }
}

// ---------------- fused QKV GEMM (z=0:Q scaled, z=1:K, z=2:V transposed) -----
// Q is pre-scaled by log2(e)/sqrt(d_model) so attention uses exp2 directly.
#define QSCALE 0.0450842200278f
__global__ __launch_bounds__(256) void gemm_qkv3(
    const u16* __restrict__ xb, const u16* __restrict__ eb,
    const u16* __restrict__ Wqb, const u16* __restrict__ Wkb,
    const u16* __restrict__ Wvb, const float* __restrict__ bq,
    const float* __restrict__ bk, const float* __restrict__ bv,
    u16* __restrict__ Qd, u16* __restrict__ Kd, u16* __restrict__ Vtd) {
  __shared__ __align__(16) u16 As[128 * 32];
  __shared__ __align__(16) u16 Bs[128 * 32];
  const int K = 1024;
  int z = blockIdx.z;
  const u16* A = (z == 0) ? xb : eb;
  const u16* W = (z == 0) ? Wqb : (z == 1) ? Wkb : Wvb;
  const float* bias = (z == 0) ? bq : (z == 1) ? bk : bv;

  int tid = threadIdx.x;
  int w = tid >> 6, lane = tid & 63;
  int wr = w >> 1, wc = w & 1;
  int r16 = lane & 15, c4 = lane >> 4;
  int m0 = blockIdx.y * 128, n0 = blockIdx.x * 128;
  int srow = tid >> 2;
  int scol = (tid & 3) * 8;

  f32x4 acc[4][4] = {};

  const u16* ga0 = A + (size_t)(m0 + srow) * K + scol;
  const u16* gb0 = W + (size_t)(n0 + srow) * K + scol;
  char* asb = (char*)As + w * 1024;
  char* bsb = (char*)Bs + w * 1024;

  for (int k0 = 0; k0 < K; k0 += 32) {
    GLOAD_LDS16(ga0 + k0, asb);
    GLOAD_LDS16(ga0 + 64 * K + k0, asb + 4096);
    GLOAD_LDS16(gb0 + k0, bsb);
    GLOAD_LDS16(gb0 + 64 * K + k0, bsb + 4096);
    __syncthreads();
    bf16x8 af[4], bfr[4];
#pragma unroll
    for (int i = 0; i < 4; ++i)
      af[i] = *(const bf16x8*)(As + (wr * 64 + i * 16 + r16) * 32 + c4 * 8);
#pragma unroll
    for (int j = 0; j < 4; ++j)
      bfr[j] = *(const bf16x8*)(Bs + (wc * 64 + j * 16 + r16) * 32 + c4 * 8);
#pragma unroll
    for (int i = 0; i < 4; ++i)
#pragma unroll
      for (int j = 0; j < 4; ++j) acc[i][j] = mfma16(af[i], bfr[j], acc[i][j]);
    __syncthreads();
  }

  if (z < 2) {
    float oscale = (z == 0) ? QSCALE : 1.0f;
    u16* dst = (z == 0) ? Qd : Kd;
#pragma unroll
    for (int i = 0; i < 4; ++i) {
      int m = m0 + wr * 64 + i * 16 + c4 * 4;
      int b = m >> 11, s = m & 2047;
#pragma unroll
      for (int j = 0; j < 4; ++j) {
        int n = n0 + wc * 64 + j * 16 + r16;
        int h = n >> 6, d = n & 63;
        float bv = bias[n];
        u16* dp = dst + (((size_t)(b * 16 + h) * 2048 + s) * 64 + d);
#pragma unroll
        for (int r = 0; r < 4; ++r)
          dp[(size_t)r * 64] = f2b((acc[i][j][r] + bv) * oscale);
      }
    }
  } else {
    // V: write transposed, Vt[(bh*64+d)*2048 + s], 4 consecutive s per lane
#pragma unroll
    for (int i = 0; i < 4; ++i) {
      int m = m0 + wr * 64 + i * 16 + c4 * 4;
      int b = m >> 11, s = m & 2047;
#pragma unroll
      for (int j = 0; j < 4; ++j) {
        int n = n0 + wc * 64 + j * 16 + r16;
        int h = n >> 6, d = n & 63;
        float bv = bias[n];
        s16x4 o4;
#pragma unroll
        for (int r = 0; r < 4; ++r) o4[r] = (short)f2b(acc[i][j][r] + bv);
        *(s16x4*)(Vtd + ((size_t)((b * 16 + h) * 64 + d)) * 2048 + s) = o4;
      }
    }
  }
}

// ---------------- out-proj GEMM: Y = ctx * Wo^T + bo + X (f32) ----------------
__global__ __launch_bounds__(256) void gemm_out(const u16* __restrict__ A,
                                                const u16* __restrict__ W,
                                                const float* __restrict__ bias,
                                                const float* __restrict__ X,
                                                float* __restrict__ Y) {
  __shared__ __align__(16) u16 As[128 * 32];
  __shared__ __align__(16) u16 Bs[128 * 32];
  const int K = 1024;
  int tid = threadIdx.x;
  int w = tid >> 6, lane = tid & 63;
  int wr = w >> 1, wc = w & 1;
  int r16 = lane & 15, c4 = lane >> 4;
  int m0 = blockIdx.y * 128, n0 = blockIdx.x * 128;
  int srow = tid >> 2;
  int scol = (tid & 3) * 8;

  f32x4 acc[4][4] = {};

  const u16* ga0 = A + (size_t)(m0 + srow) * K + scol;
  const u16* gb0 = W + (size_t)(n0 + srow) * K + scol;
  char* asb = (char*)As + w * 1024;
  char* bsb = (char*)Bs + w * 1024;

  for (int k0 = 0; k0 < K; k0 += 32) {
    GLOAD_LDS16(ga0 + k0, asb);
    GLOAD_LDS16(ga0 + 64 * K + k0, asb + 4096);
    GLOAD_LDS16(gb0 + k0, bsb);
    GLOAD_LDS16(gb0 + 64 * K + k0, bsb + 4096);
    __syncthreads();
    bf16x8 af[4], bfr[4];
#pragma unroll
    for (int i = 0; i < 4; ++i)
      af[i] = *(const bf16x8*)(As + (wr * 64 + i * 16 + r16) * 32 + c4 * 8);
#pragma unroll
    for (int j = 0; j < 4; ++j)
      bfr[j] = *(const bf16x8*)(Bs + (wc * 64 + j * 16 + r16) * 32 + c4 * 8);
#pragma unroll
    for (int i = 0; i < 4; ++i)
#pragma unroll
      for (int j = 0; j < 4; ++j) acc[i][j] = mfma16(af[i], bfr[j], acc[i][j]);
    __syncthreads();
  }

#pragma unroll
  for (int i = 0; i < 4; ++i) {
    int m = m0 + wr * 64 + i * 16 + c4 * 4;
#pragma unroll
    for (int j = 0; j < 4; ++j) {
      int n = n0 + wc * 64 + j * 16 + r16;
      float bv = bias[n];
#pragma unroll
      for (int r = 0; r < 4; ++r) {
        size_t idx = (size_t)(m + r) * 1024 + n;
        Y[idx] = acc[i][j][r] + bv + X[idx];
      }
    }
  }
}

// ---------------- fused attention v5: LDS-staged flash structure -------------
// Block = 4 waves x 32 q = 128 q rows. K/V tiles (64 kv) staged to LDS via
// global_load_lds (no VGPR cost -> compiler can't delete the pipeline),
// double-buffered, one barrier per step. LDS content is chunk-swizzled via the
// per-lane GLOBAL source address (dest must stay linear); reads XOR the same
// swizzle -> 2-way banks (free). S^T = mfma(K,Q) with permuted K-row map so
// PV's A-fragment is lane-local. Q pre-scaled by log2e/32; normalizer folded
// into the exponent. 1D grid id = qt*32+bh -> XCD(id%8)=bh%8 keeps K/V of a
// bh resident in one XCD's L2.
__global__ __launch_bounds__(256, 2) void attn_k(const u16* __restrict__ Q,
                                                 const u16* __restrict__ Kg,
                                                 const u16* __restrict__ Vt,
                                                 float* __restrict__ attnw,
                                                 u16* __restrict__ ctx) {
  __shared__ __align__(16) u16 Klds[2][64 * 64];
  __shared__ __align__(16) u16 Vlds[2][64 * 64];

  int tid = threadIdx.x;
  int w = tid >> 6, lane = tid & 63;
  int r16 = lane & 15, c4 = lane >> 4;
  int id = blockIdx.x;
  int bh = id & 31, qt = id >> 5;
  int b = bh >> 4, h = bh & 15;
  int q0 = qt * 128 + w * 32;

  const u16* Qp = Q + ((size_t)bh * 2048 + q0) * 64;
  const u16* Kp = Kg + (size_t)bh * 2048 * 64;
  const u16* Vp = Vt + (size_t)bh * 64 * 2048;

  // Q B-fragments: qf[half][chunk] = Q[q0+half*16+r16][chunk*32 + c4*8 ..]
  bf16x8 qf[2][2];
#pragma unroll
  for (int hh = 0; hh < 2; ++hh)
#pragma unroll
    for (int ch = 0; ch < 2; ++ch)
      qf[hh][ch] = *(const bf16x8*)(Qp + (size_t)(hh * 16 + r16) * 64 +
                                    ch * 32 + c4 * 8);

  int perm0 = ((r16 >> 2) << 3) + (r16 & 3);
  // staging lane constants: instr i covers LDS row i*32 + w*8 + lane/8
  int srow0 = w * 8 + (lane >> 3);
  int sc = lane & 7;

// stage K tile rows [kv..kv+64) into Klds[bufi] (content chunk-swizzled)
#define STAGE_K(bufi, kv)                                                      \
  {                                                                            \
    _Pragma("unroll") for (int i = 0; i < 2; ++i) {                            \
      int row = i * 32 + srow0;                                                \
      int ch = sc ^ fsw(row);                                                  \
      GLOAD_LDS16(Kp + (size_t)((kv) + row) * 64 + ch * 8,                     \
                  (u16*)&Klds[bufi][0] + w * 512 + i * 2048);                  \
    }                                                                          \
  }
// stage V tile cols [kv..kv+64) of all 64 d-rows into Vlds[bufi]
#define STAGE_V(bufi, kv)                                                      \
  {                                                                            \
    _Pragma("unroll") for (int i = 0; i < 2; ++i) {                            \
      int row = i * 32 + srow0;                                                \
      int ch = sc ^ fsw(row);                                                  \
      GLOAD_LDS16(Vp + (size_t)row * 2048 + (kv) + ch * 8,                     \
                  (u16*)&Vlds[bufi][0] + w * 512 + i * 2048);                  \
    }                                                                          \
  }
// read a 16B K/V fragment: row, chunk (0..7) with swizzle undo
#define LDSF(base, row, chunk)                                                 \
  (*(const bf16x8*)((base) + (row) * 64 + (((chunk) ^ fsw(row)) << 3)))

  // ---------------- pass 1: row sums of exp2(S) ----------------
  float sumA = 0.f, sumB = 0.f;
  STAGE_K(0, 0);
  __syncthreads();
  int buf = 0;
  for (int kv0 = 0; kv0 < 2048; kv0 += 64) {
    if (kv0 + 64 < 2048) STAGE_K(buf ^ 1, kv0 + 64);
    const u16* Kb = &Klds[buf][0];
#pragma unroll
    for (int s = 0; s < 2; ++s) {
      int ra = s * 32 + perm0;
      bf16x8 k00 = LDSF(Kb, ra, c4);
      bf16x8 k01 = LDSF(Kb, ra, c4 + 4);
      bf16x8 k10 = LDSF(Kb, ra + 4, c4);
      bf16x8 k11 = LDSF(Kb, ra + 4, c4 + 4);
      f32x4 s0A = {}, s1A = {}, s0B = {}, s1B = {};
      __builtin_amdgcn_s_setprio(1);
      s0A = mfma16(k00, qf[0][0], s0A);
      s0A = mfma16(k01, qf[0][1], s0A);
      s1A = mfma16(k10, qf[0][0], s1A);
      s1A = mfma16(k11, qf[0][1], s1A);
      s0B = mfma16(k00, qf[1][0], s0B);
      s0B = mfma16(k01, qf[1][1], s0B);
      s1B = mfma16(k10, qf[1][0], s1B);
      s1B = mfma16(k11, qf[1][1], s1B);
      __builtin_amdgcn_s_setprio(0);
#pragma unroll
      for (int r = 0; r < 4; ++r) {
        sumA += __builtin_amdgcn_exp2f(s0A[r]) + __builtin_amdgcn_exp2f(s1A[r]);
        sumB += __builtin_amdgcn_exp2f(s0B[r]) + __builtin_amdgcn_exp2f(s1B[r]);
      }
    }
    __syncthreads();
    buf ^= 1;
  }
  sumA += __shfl_xor(sumA, 16, 64);
  sumA += __shfl_xor(sumA, 32, 64);
  sumB += __shfl_xor(sumB, 16, 64);
  sumB += __shfl_xor(sumB, 32, 64);
  float nlsA = -__log2f(sumA);
  float nlsB = -__log2f(sumB);

  // ---------------- pass 2: P write + ctx = P*V ----------------
  f32x4 oA[4] = {}, oB[4] = {};
  float* apA = attnw + ((size_t)bh * 2048 + q0 + r16) * 2048;
  float* apB = apA + (size_t)16 * 2048;
  STAGE_K(0, 0);
  STAGE_V(0, 0);
  __syncthreads();
  buf = 0;
  for (int kv0 = 0; kv0 < 2048; kv0 += 64) {
    if (kv0 + 64 < 2048) {
      STAGE_K(buf ^ 1, kv0 + 64);
      STAGE_V(buf ^ 1, kv0 + 64);
    }
    const u16* Kb = &Klds[buf][0];
    const u16* Vb = &Vlds[buf][0];
#pragma unroll
    for (int s = 0; s < 2; ++s) {
      int ra = s * 32 + perm0;
      bf16x8 k00 = LDSF(Kb, ra, c4);
      bf16x8 k01 = LDSF(Kb, ra, c4 + 4);
      bf16x8 k10 = LDSF(Kb, ra + 4, c4);
      bf16x8 k11 = LDSF(Kb, ra + 4, c4 + 4);
      f32x4 s0A = {}, s1A = {}, s0B = {}, s1B = {};
      __builtin_amdgcn_s_setprio(1);
      s0A = mfma16(k00, qf[0][0], s0A);
      s0A = mfma16(k01, qf[0][1], s0A);
      s1A = mfma16(k10, qf[0][0], s1A);
      s1A = mfma16(k11, qf[0][1], s1A);
      s0B = mfma16(k00, qf[1][0], s0B);
      s0B = mfma16(k01, qf[1][1], s0B);
      s1B = mfma16(k10, qf[1][0], s1B);
      s1B = mfma16(k11, qf[1][1], s1B);
      __builtin_amdgcn_s_setprio(0);
      f32x4 p0A, p1A, p0B, p1B;
#pragma unroll
      for (int r = 0; r < 4; ++r) {
        p0A[r] = __builtin_amdgcn_exp2f(s0A[r] + nlsA);
        p1A[r] = __builtin_amdgcn_exp2f(s1A[r] + nlsA);
        p0B[r] = __builtin_amdgcn_exp2f(s0B[r] + nlsB);
        p1B[r] = __builtin_amdgcn_exp2f(s1B[r] + nlsB);
      }
      int kvc = kv0 + s * 32 + c4 * 8;
      *(f32x4*)(apA + kvc) = p0A;
      *(f32x4*)(apA + kvc + 4) = p1A;
      *(f32x4*)(apB + kvc) = p0B;
      *(f32x4*)(apB + kvc + 4) = p1B;
      bf16x8 pfA, pfB;
#pragma unroll
      for (int r = 0; r < 4; ++r) {
        pfA[r] = (short)f2b(p0A[r]);
        pfA[r + 4] = (short)f2b(p1A[r]);
        pfB[r] = (short)f2b(p0B[r]);
        pfB[r + 4] = (short)f2b(p1B[r]);
      }
      bf16x8 v0 = LDSF(Vb, 0 * 16 + r16, s * 4 + c4);
      bf16x8 v1 = LDSF(Vb, 1 * 16 + r16, s * 4 + c4);
      bf16x8 v2 = LDSF(Vb, 2 * 16 + r16, s * 4 + c4);
      bf16x8 v3 = LDSF(Vb, 3 * 16 + r16, s * 4 + c4);
      __builtin_amdgcn_s_setprio(1);
      oA[0] = mfma16(pfA, v0, oA[0]);
      oA[1] = mfma16(pfA, v1, oA[1]);
      oA[2] = mfma16(pfA, v2, oA[2]);
      oA[3] = mfma16(pfA, v3, oA[3]);
      oB[0] = mfma16(pfB, v0, oB[0]);
      oB[1] = mfma16(pfB, v1, oB[1]);
      oB[2] = mfma16(pfB, v2, oB[2]);
      oB[3] = mfma16(pfB, v3, oB[3]);
      __builtin_amdgcn_s_setprio(0);
    }
    __syncthreads();
    buf ^= 1;
  }

#pragma unroll
  for (int dt = 0; dt < 4; ++dt)
#pragma unroll
    for (int r = 0; r < 4; ++r) {
      ctx[((size_t)(b * 2048 + q0 + c4 * 4 + r)) * 1024 + h * 64 + dt * 16 +
          r16] = f2b(oA[dt][r]);
      ctx[((size_t)(b * 2048 + q0 + 16 + c4 * 4 + r)) * 1024 + h * 64 +
          dt * 16 + r16] = f2b(oB[dt][r]);
    }
#undef STAGE_K
#undef STAGE_V
#undef LDSF
}

// ---------------- LayerNorm over last dim (1024), wave per row ----------------
__global__ __launch_bounds__(256) void ln_k(const float* __restrict__ Y,
                                            const float* __restrict__ gamma,
                                            const float* __restrict__ beta,
                                            float* __restrict__ out) {
  int row = blockIdx.x * 4 + (threadIdx.x >> 6);
  int lane = threadIdx.x & 63;
  const float* yr = Y + (size_t)row * 1024;
  float4 v[4];
  float sum = 0.f, sq = 0.f;
#pragma unroll
  for (int i = 0; i < 4; ++i) {
    v[i] = *(const float4*)(yr + i * 256 + lane * 4);
    sum += v[i].x + v[i].y + v[i].z + v[i].w;
    sq += v[i].x * v[i].x + v[i].y * v[i].y + v[i].z * v[i].z + v[i].w * v[i].w;
  }
#pragma unroll
  for (int m = 1; m < 64; m <<= 1) {
    sum += __shfl_xor(sum, m, 64);
    sq += __shfl_xor(sq, m, 64);
  }
  float mu = sum * (1.f / 1024.f);
  float var = sq * (1.f / 1024.f) - mu * mu;
  float rs = rsqrtf(var + 1e-5f);
  float* orow = out + (size_t)row * 1024;
#pragma unroll
  for (int i = 0; i < 4; ++i) {
    int c = i * 256 + lane * 4;
    float4 g = *(const float4*)(gamma + c);
    float4 be = *(const float4*)(beta + c);
    float4 o;
    o.x = (v[i].x - mu) * rs * g.x + be.x;
    o.y = (v[i].y - mu) * rs * g.y + be.y;
    o.z = (v[i].z - mu) * rs * g.z + be.z;
    o.w = (v[i].w - mu) * rs * g.w + be.w;
    *(float4*)(orow + c) = o;
  }
}

extern "C" void kernel_launch(void* const* d_in, const int* in_sizes, int n_in,
                              void* d_out, int out_size, void* d_ws,
                              size_t ws_size, hipStream_t stream) {
  const float* x = (const float*)d_in[0];
  const float* enc = (const float*)d_in[1];
  const float* Wq = (const float*)d_in[2];
  const float* bq = (const float*)d_in[3];
  const float* Wk = (const float*)d_in[4];
  const float* bk = (const float*)d_in[5];
  const float* Wv = (const float*)d_in[6];
  const float* bv = (const float*)d_in[7];
  const float* Wo = (const float*)d_in[8];
  const float* bo = (const float*)d_in[9];
  const float* gamma = (const float*)d_in[10];
  const float* beta = (const float*)d_in[11];

  float* out = (float*)d_out;
  float* attnw = out + (size_t)4194304;  // 2*2048*1024

  char* ws = (char*)d_ws;
  u16* xb = (u16*)(ws + (size_t)0);
  u16* eb = (u16*)(ws + ((size_t)8 << 20));
  u16* Wqb = (u16*)(ws + ((size_t)16 << 20));
  u16* Wkb = (u16*)(ws + ((size_t)18 << 20));
  u16* Wvb = (u16*)(ws + ((size_t)20 << 20));
  u16* Wob = (u16*)(ws + ((size_t)22 << 20));
  u16* Qws = (u16*)(ws + ((size_t)24 << 20));
  u16* Kws = (u16*)(ws + ((size_t)32 << 20));
  u16* Vt = (u16*)(ws + ((size_t)48 << 20));
  u16* ctx = (u16*)(ws + ((size_t)40 << 20));
  float* Yws = (float*)(ws + (size_t)0);  // reuse xb/eb (dead after gemms)

  cvt_bf16<<<dim3(1024), 256, 0, stream>>>(x, xb, 1048576);
  cvt_bf16<<<dim3(1024), 256, 0, stream>>>(enc, eb, 1048576);
  cvt_bf16<<<dim3(256), 256, 0, stream>>>(Wq, Wqb, 262144);
  cvt_bf16<<<dim3(256), 256, 0, stream>>>(Wk, Wkb, 262144);
  cvt_bf16<<<dim3(256), 256, 0, stream>>>(Wv, Wvb, 262144);
  cvt_bf16<<<dim3(256), 256, 0, stream>>>(Wo, Wob, 262144);

  gemm_qkv3<<<dim3(8, 32, 3), 256, 0, stream>>>(xb, eb, Wqb, Wkb, Wvb, bq, bk,
                                                bv, Qws, Kws, Vt);

  attn_k<<<dim3(512), 256, 0, stream>>>(Qws, Kws, Vt, attnw, ctx);

  gemm_out<<<dim3(8, 32), 256, 0, stream>>>(ctx, Wob, bo, x, Yws);

  ln_k<<<dim3(1024), 256, 0, stream>>>(Yws, gamma, beta, out);
}

// Round 6
// 304.274 us; speedup vs baseline: 1.6977x; 1.0215x over previous
//
#include <hip/hip_runtime.h>

typedef __attribute__((ext_vector_type(4))) float f32x4;
typedef __attribute__((ext_vector_type(8))) short bf16x8;
typedef __attribute__((ext_vector_type(4))) short s16x4;
typedef __attribute__((ext_vector_type(4))) unsigned u32x4;
typedef unsigned short u16;

#define GLOAD_LDS16(g, l)                                                      \
  __builtin_amdgcn_global_load_lds(                                            \
      (__attribute__((address_space(1))) const void*)(g),                      \
      (__attribute__((address_space(3))) void*)(l), 16, 0, 0)

static __device__ __forceinline__ u16 f2b(float f) {
  unsigned u = __builtin_bit_cast(unsigned, f);
  unsigned r = (u + 0x7fffu + ((u >> 16) & 1u)) >> 16;
  return (u16)r;
}

// packed f32x2 -> bf16x2 (RNE, matches f2b); no builtin on gfx950
static __device__ __forceinline__ unsigned pk2(float lo, float hi) {
  unsigned r;
  asm("v_cvt_pk_bf16_f32 %0, %1, %2" : "=v"(r) : "v"(lo), "v"(hi));
  return r;
}

static __device__ __forceinline__ f32x4 mfma16(bf16x8 a, bf16x8 b, f32x4 c) {
  return __builtin_amdgcn_mfma_f32_16x16x32_bf16(a, b, c, 0, 0, 0);
}

// bank swizzle: chunk' = chunk ^ fsw(row); fsw spreads the 8 16B-chunks of a
// 128B row across rows so MFMA-fragment reads are 2-way (free) not 16-way.
static __device__ __forceinline__ int fsw(int row) {
  return (row & 7) ^ ((row & 8) >> 1);
}

// ---------------- f32 -> bf16 convert ----------------
__global__ __launch_bounds__(256) void cvt_bf16(const float* __restrict__ in,
                                                u16* __restrict__ out, int n4) {
  int i = blockIdx.x * 256 + threadIdx.x;
  int stride = gridDim.x * 256;
  for (; i < n4; i += stride) {
    float4 v = ((const float4*)in)[i];
    s16x4 o;
    o[0] = (short)f2b(v.x);
    o[1] = (short)f2b(v.y);
    o[2] = (short)f2b(v.z);
    o[3] = (short)f2b(v.w);
    ((s16x4*)out)[i] = o;
  }
}

// ---------------- fused QKV GEMM (z=0:Q scaled, z=1:K, z=2:V transposed) -----
// Q is pre-scaled by log2(e)/sqrt(d_model) so attention uses exp2 directly.
#define QSCALE 0.0450842200278f
__global__ __launch_bounds__(256) void gemm_qkv3(
    const u16* __restrict__ xb, const u16* __restrict__ eb,
    const u16* __restrict__ Wqb, const u16* __restrict__ Wkb,
    const u16* __restrict__ Wvb, const float* __restrict__ bq,
    const float* __restrict__ bk, const float* __restrict__ bv,
    u16* __restrict__ Qd, u16* __restrict__ Kd, u16* __restrict__ Vtd) {
  __shared__ __align__(16) u16 As[128 * 32];
  __shared__ __align__(16) u16 Bs[128 * 32];
  const int K = 1024;
  int z = blockIdx.z;
  const u16* A = (z == 0) ? xb : eb;
  const u16* W = (z == 0) ? Wqb : (z == 1) ? Wkb : Wvb;
  const float* bias = (z == 0) ? bq : (z == 1) ? bk : bv;

  int tid = threadIdx.x;
  int w = tid >> 6, lane = tid & 63;
  int wr = w >> 1, wc = w & 1;
  int r16 = lane & 15, c4 = lane >> 4;
  int m0 = blockIdx.y * 128, n0 = blockIdx.x * 128;
  int srow = tid >> 2;
  int scol = (tid & 3) * 8;

  f32x4 acc[4][4] = {};

  const u16* ga0 = A + (size_t)(m0 + srow) * K + scol;
  const u16* gb0 = W + (size_t)(n0 + srow) * K + scol;
  char* asb = (char*)As + w * 1024;
  char* bsb = (char*)Bs + w * 1024;

  for (int k0 = 0; k0 < K; k0 += 32) {
    GLOAD_LDS16(ga0 + k0, asb);
    GLOAD_LDS16(ga0 + 64 * K + k0, asb + 4096);
    GLOAD_LDS16(gb0 + k0, bsb);
    GLOAD_LDS16(gb0 + 64 * K + k0, bsb + 4096);
    __syncthreads();
    bf16x8 af[4], bfr[4];
#pragma unroll
    for (int i = 0; i < 4; ++i)
      af[i] = *(const bf16x8*)(As + (wr * 64 + i * 16 + r16) * 32 + c4 * 8);
#pragma unroll
    for (int j = 0; j < 4; ++j)
      bfr[j] = *(const bf16x8*)(Bs + (wc * 64 + j * 16 + r16) * 32 + c4 * 8);
#pragma unroll
    for (int i = 0; i < 4; ++i)
#pragma unroll
      for (int j = 0; j < 4; ++j) acc[i][j] = mfma16(af[i], bfr[j], acc[i][j]);
    __syncthreads();
  }

  if (z < 2) {
    float oscale = (z == 0) ? QSCALE : 1.0f;
    u16* dst = (z == 0) ? Qd : Kd;
#pragma unroll
    for (int i = 0; i < 4; ++i) {
      int m = m0 + wr * 64 + i * 16 + c4 * 4;
      int b = m >> 11, s = m & 2047;
#pragma unroll
      for (int j = 0; j < 4; ++j) {
        int n = n0 + wc * 64 + j * 16 + r16;
        int h = n >> 6, d = n & 63;
        float bv = bias[n];
        u16* dp = dst + (((size_t)(b * 16 + h) * 2048 + s) * 64 + d);
#pragma unroll
        for (int r = 0; r < 4; ++r)
          dp[(size_t)r * 64] = f2b((acc[i][j][r] + bv) * oscale);
      }
    }
  } else {
    // V: write transposed, Vt[(bh*64+d)*2048 + s], 4 consecutive s per lane
#pragma unroll
    for (int i = 0; i < 4; ++i) {
      int m = m0 + wr * 64 + i * 16 + c4 * 4;
      int b = m >> 11, s = m & 2047;
#pragma unroll
      for (int j = 0; j < 4; ++j) {
        int n = n0 + wc * 64 + j * 16 + r16;
        int h = n >> 6, d = n & 63;
        float bv = bias[n];
        s16x4 o4;
#pragma unroll
        for (int r = 0; r < 4; ++r) o4[r] = (short)f2b(acc[i][j][r] + bv);
        *(s16x4*)(Vtd + ((size_t)((b * 16 + h) * 64 + d)) * 2048 + s) = o4;
      }
    }
  }
}

// ---------------- out-proj GEMM: Y = ctx * Wo^T + bo + X (f32) ----------------
__global__ __launch_bounds__(256) void gemm_out(const u16* __restrict__ A,
                                                const u16* __restrict__ W,
                                                const float* __restrict__ bias,
                                                const float* __restrict__ X,
                                                float* __restrict__ Y) {
  __shared__ __align__(16) u16 As[128 * 32];
  __shared__ __align__(16) u16 Bs[128 * 32];
  const int K = 1024;
  int tid = threadIdx.x;
  int w = tid >> 6, lane = tid & 63;
  int wr = w >> 1, wc = w & 1;
  int r16 = lane & 15, c4 = lane >> 4;
  int m0 = blockIdx.y * 128, n0 = blockIdx.x * 128;
  int srow = tid >> 2;
  int scol = (tid & 3) * 8;

  f32x4 acc[4][4] = {};

  const u16* ga0 = A + (size_t)(m0 + srow) * K + scol;
  const u16* gb0 = W + (size_t)(n0 + srow) * K + scol;
  char* asb = (char*)As + w * 1024;
  char* bsb = (char*)Bs + w * 1024;

  for (int k0 = 0; k0 < K; k0 += 32) {
    GLOAD_LDS16(ga0 + k0, asb);
    GLOAD_LDS16(ga0 + 64 * K + k0, asb + 4096);
    GLOAD_LDS16(gb0 + k0, bsb);
    GLOAD_LDS16(gb0 + 64 * K + k0, bsb + 4096);
    __syncthreads();
    bf16x8 af[4], bfr[4];
#pragma unroll
    for (int i = 0; i < 4; ++i)
      af[i] = *(const bf16x8*)(As + (wr * 64 + i * 16 + r16) * 32 + c4 * 8);
#pragma unroll
    for (int j = 0; j < 4; ++j)
      bfr[j] = *(const bf16x8*)(Bs + (wc * 64 + j * 16 + r16) * 32 + c4 * 8);
#pragma unroll
    for (int i = 0; i < 4; ++i)
#pragma unroll
      for (int j = 0; j < 4; ++j) acc[i][j] = mfma16(af[i], bfr[j], acc[i][j]);
    __syncthreads();
  }

#pragma unroll
  for (int i = 0; i < 4; ++i) {
    int m = m0 + wr * 64 + i * 16 + c4 * 4;
#pragma unroll
    for (int j = 0; j < 4; ++j) {
      int n = n0 + wc * 64 + j * 16 + r16;
      float bv = bias[n];
#pragma unroll
      for (int r = 0; r < 4; ++r) {
        size_t idx = (size_t)(m + r) * 1024 + n;
        Y[idx] = acc[i][j][r] + bv + X[idx];
      }
    }
  }
}

// ---------------- fused attention v6: LDS flash, 64q blocks, 4 blocks/CU -----
// Block = 4 waves x 16 q = 64 q rows; grid 1024 -> 4 blocks/CU, 16 waves/CU.
// K/V staged via global_load_lds (swizzled via per-lane GLOBAL source, linear
// dest), double-buffered, one barrier/step. S^T = mfma(K,Q), permuted K-row
// map -> PV A-fragment lane-local. Q pre-scaled by log2e/32; normalizer in
// exponent. id%32 = bh -> XCD(id%8)=bh%8 keeps each bh's K/V in one L2.
__global__ __launch_bounds__(256, 4) void attn_k(const u16* __restrict__ Q,
                                                 const u16* __restrict__ Kg,
                                                 const u16* __restrict__ Vt,
                                                 float* __restrict__ attnw,
                                                 u16* __restrict__ ctx) {
  __shared__ __align__(16) u16 Klds[2][64 * 64];
  __shared__ __align__(16) u16 Vlds[2][64 * 64];

  int tid = threadIdx.x;
  int w = tid >> 6, lane = tid & 63;
  int r16 = lane & 15, c4 = lane >> 4;
  int id = blockIdx.x;
  int bh = id & 31, qt = id >> 5;
  int b = bh >> 4, h = bh & 15;
  int q0 = qt * 64 + w * 16;

  const u16* Qp = Q + ((size_t)bh * 2048 + q0) * 64;
  const u16* Kp = Kg + (size_t)bh * 2048 * 64;
  const u16* Vp = Vt + (size_t)bh * 64 * 2048;

  // Q B-fragments: qf[ch] = Q[q0+r16][ch*32 + c4*8 ..]
  bf16x8 qf0 = *(const bf16x8*)(Qp + (size_t)r16 * 64 + c4 * 8);
  bf16x8 qf1 = *(const bf16x8*)(Qp + (size_t)r16 * 64 + 32 + c4 * 8);

  int perm0 = ((r16 >> 2) << 3) + (r16 & 3);
  // staging lane constants: instr i covers LDS row i*32 + w*8 + lane/8
  int srow0 = w * 8 + (lane >> 3);
  int sc = lane & 7;

// stage K tile rows [kv..kv+64) into Klds[bufi] (content chunk-swizzled)
#define STAGE_K(bufi, kv)                                                      \
  {                                                                            \
    _Pragma("unroll") for (int i = 0; i < 2; ++i) {                            \
      int row = i * 32 + srow0;                                                \
      int ch = sc ^ fsw(row);                                                  \
      GLOAD_LDS16(Kp + (size_t)((kv) + row) * 64 + ch * 8,                     \
                  (u16*)&Klds[bufi][0] + w * 512 + i * 2048);                  \
    }                                                                          \
  }
// stage V tile cols [kv..kv+64) of all 64 d-rows into Vlds[bufi]
#define STAGE_V(bufi, kv)                                                      \
  {                                                                            \
    _Pragma("unroll") for (int i = 0; i < 2; ++i) {                            \
      int row = i * 32 + srow0;                                                \
      int ch = sc ^ fsw(row);                                                  \
      GLOAD_LDS16(Vp + (size_t)row * 2048 + (kv) + ch * 8,                     \
                  (u16*)&Vlds[bufi][0] + w * 512 + i * 2048);                  \
    }                                                                          \
  }
// read a 16B K/V fragment: row, chunk (0..7) with swizzle undo
#define LDSF(base, row, chunk)                                                 \
  (*(const bf16x8*)((base) + (row) * 64 + (((chunk) ^ fsw(row)) << 3)))

  // ---------------- pass 1: row sums of exp2(S) ----------------
  float sum = 0.f;
  STAGE_K(0, 0);
  __syncthreads();
  int buf = 0;
  for (int kv0 = 0; kv0 < 2048; kv0 += 64) {
    if (kv0 + 64 < 2048) STAGE_K(buf ^ 1, kv0 + 64);
    const u16* Kb = &Klds[buf][0];
#pragma unroll
    for (int s = 0; s < 2; ++s) {
      int ra = s * 32 + perm0;
      bf16x8 k00 = LDSF(Kb, ra, c4);
      bf16x8 k01 = LDSF(Kb, ra, c4 + 4);
      bf16x8 k10 = LDSF(Kb, ra + 4, c4);
      bf16x8 k11 = LDSF(Kb, ra + 4, c4 + 4);
      f32x4 s0 = {}, s1 = {};
      __builtin_amdgcn_s_setprio(1);
      s0 = mfma16(k00, qf0, s0);
      s0 = mfma16(k01, qf1, s0);
      s1 = mfma16(k10, qf0, s1);
      s1 = mfma16(k11, qf1, s1);
      __builtin_amdgcn_s_setprio(0);
#pragma unroll
      for (int r = 0; r < 4; ++r)
        sum += __builtin_amdgcn_exp2f(s0[r]) + __builtin_amdgcn_exp2f(s1[r]);
    }
    __syncthreads();
    buf ^= 1;
  }
  sum += __shfl_xor(sum, 16, 64);
  sum += __shfl_xor(sum, 32, 64);
  float nls = -__log2f(sum);

  // ---------------- pass 2: P write + ctx = P*V ----------------
  f32x4 o[4] = {};
  float* ap = attnw + ((size_t)bh * 2048 + q0 + r16) * 2048;
  STAGE_K(0, 0);
  STAGE_V(0, 0);
  __syncthreads();
  buf = 0;
  for (int kv0 = 0; kv0 < 2048; kv0 += 64) {
    if (kv0 + 64 < 2048) {
      STAGE_K(buf ^ 1, kv0 + 64);
      STAGE_V(buf ^ 1, kv0 + 64);
    }
    const u16* Kb = &Klds[buf][0];
    const u16* Vb = &Vlds[buf][0];
#pragma unroll
    for (int s = 0; s < 2; ++s) {
      int ra = s * 32 + perm0;
      bf16x8 k00 = LDSF(Kb, ra, c4);
      bf16x8 k01 = LDSF(Kb, ra, c4 + 4);
      bf16x8 k10 = LDSF(Kb, ra + 4, c4);
      bf16x8 k11 = LDSF(Kb, ra + 4, c4 + 4);
      f32x4 s0 = {}, s1 = {};
      __builtin_amdgcn_s_setprio(1);
      s0 = mfma16(k00, qf0, s0);
      s0 = mfma16(k01, qf1, s0);
      s1 = mfma16(k10, qf0, s1);
      s1 = mfma16(k11, qf1, s1);
      __builtin_amdgcn_s_setprio(0);
      f32x4 p0, p1;
#pragma unroll
      for (int r = 0; r < 4; ++r) {
        p0[r] = __builtin_amdgcn_exp2f(s0[r] + nls);
        p1[r] = __builtin_amdgcn_exp2f(s1[r] + nls);
      }
      int kvc = kv0 + s * 32 + c4 * 8;
      *(f32x4*)(ap + kvc) = p0;
      *(f32x4*)(ap + kvc + 4) = p1;
      u32x4 pk;
      pk[0] = pk2(p0[0], p0[1]);
      pk[1] = pk2(p0[2], p0[3]);
      pk[2] = pk2(p1[0], p1[1]);
      pk[3] = pk2(p1[2], p1[3]);
      bf16x8 pf = __builtin_bit_cast(bf16x8, pk);
      bf16x8 v0 = LDSF(Vb, 0 * 16 + r16, s * 4 + c4);
      bf16x8 v1 = LDSF(Vb, 1 * 16 + r16, s * 4 + c4);
      bf16x8 v2 = LDSF(Vb, 2 * 16 + r16, s * 4 + c4);
      bf16x8 v3 = LDSF(Vb, 3 * 16 + r16, s * 4 + c4);
      __builtin_amdgcn_s_setprio(1);
      o[0] = mfma16(pf, v0, o[0]);
      o[1] = mfma16(pf, v1, o[1]);
      o[2] = mfma16(pf, v2, o[2]);
      o[3] = mfma16(pf, v3, o[3]);
      __builtin_amdgcn_s_setprio(0);
    }
    __syncthreads();
    buf ^= 1;
  }

#pragma unroll
  for (int dt = 0; dt < 4; ++dt)
#pragma unroll
    for (int r = 0; r < 4; ++r)
      ctx[((size_t)(b * 2048 + q0 + c4 * 4 + r)) * 1024 + h * 64 + dt * 16 +
          r16] = f2b(o[dt][r]);
#undef STAGE_K
#undef STAGE_V
#undef LDSF
}

// ---------------- LayerNorm over last dim (1024), wave per row ----------------
__global__ __launch_bounds__(256) void ln_k(const float* __restrict__ Y,
                                            const float* __restrict__ gamma,
                                            const float* __restrict__ beta,
                                            float* __restrict__ out) {
  int row = blockIdx.x * 4 + (threadIdx.x >> 6);
  int lane = threadIdx.x & 63;
  const float* yr = Y + (size_t)row * 1024;
  float4 v[4];
  float sum = 0.f, sq = 0.f;
#pragma unroll
  for (int i = 0; i < 4; ++i) {
    v[i] = *(const float4*)(yr + i * 256 + lane * 4);
    sum += v[i].x + v[i].y + v[i].z + v[i].w;
    sq += v[i].x * v[i].x + v[i].y * v[i].y + v[i].z * v[i].z + v[i].w * v[i].w;
  }
#pragma unroll
  for (int m = 1; m < 64; m <<= 1) {
    sum += __shfl_xor(sum, m, 64);
    sq += __shfl_xor(sq, m, 64);
  }
  float mu = sum * (1.f / 1024.f);
  float var = sq * (1.f / 1024.f) - mu * mu;
  float rs = rsqrtf(var + 1e-5f);
  float* orow = out + (size_t)row * 1024;
#pragma unroll
  for (int i = 0; i < 4; ++i) {
    int c = i * 256 + lane * 4;
    float4 g = *(const float4*)(gamma + c);
    float4 be = *(const float4*)(beta + c);
    float4 o;
    o.x = (v[i].x - mu) * rs * g.x + be.x;
    o.y = (v[i].y - mu) * rs * g.y + be.y;
    o.z = (v[i].z - mu) * rs * g.z + be.z;
    o.w = (v[i].w - mu) * rs * g.w + be.w;
    *(float4*)(orow + c) = o;
  }
}

extern "C" void kernel_launch(void* const* d_in, const int* in_sizes, int n_in,
                              void* d_out, int out_size, void* d_ws,
                              size_t ws_size, hipStream_t stream) {
  const float* x = (const float*)d_in[0];
  const float* enc = (const float*)d_in[1];
  const float* Wq = (const float*)d_in[2];
  const float* bq = (const float*)d_in[3];
  const float* Wk = (const float*)d_in[4];
  const float* bk = (const float*)d_in[5];
  const float* Wv = (const float*)d_in[6];
  const float* bv = (const float*)d_in[7];
  const float* Wo = (const float*)d_in[8];
  const float* bo = (const float*)d_in[9];
  const float* gamma = (const float*)d_in[10];
  const float* beta = (const float*)d_in[11];

  float* out = (float*)d_out;
  float* attnw = out + (size_t)4194304;  // 2*2048*1024

  char* ws = (char*)d_ws;
  u16* xb = (u16*)(ws + (size_t)0);
  u16* eb = (u16*)(ws + ((size_t)8 << 20));
  u16* Wqb = (u16*)(ws + ((size_t)16 << 20));
  u16* Wkb = (u16*)(ws + ((size_t)18 << 20));
  u16* Wvb = (u16*)(ws + ((size_t)20 << 20));
  u16* Wob = (u16*)(ws + ((size_t)22 << 20));
  u16* Qws = (u16*)(ws + ((size_t)24 << 20));
  u16* Kws = (u16*)(ws + ((size_t)32 << 20));
  u16* Vt = (u16*)(ws + ((size_t)48 << 20));
  u16* ctx = (u16*)(ws + ((size_t)40 << 20));
  float* Yws = (float*)(ws + (size_t)0);  // reuse xb/eb (dead after gemms)

  cvt_bf16<<<dim3(1024), 256, 0, stream>>>(x, xb, 1048576);
  cvt_bf16<<<dim3(1024), 256, 0, stream>>>(enc, eb, 1048576);
  cvt_bf16<<<dim3(256), 256, 0, stream>>>(Wq, Wqb, 262144);
  cvt_bf16<<<dim3(256), 256, 0, stream>>>(Wk, Wkb, 262144);
  cvt_bf16<<<dim3(256), 256, 0, stream>>>(Wv, Wvb, 262144);
  cvt_bf16<<<dim3(256), 256, 0, stream>>>(Wo, Wob, 262144);

  gemm_qkv3<<<dim3(8, 32, 3), 256, 0, stream>>>(xb, eb, Wqb, Wkb, Wvb, bq, bk,
                                                bv, Qws, Kws, Vt);

  attn_k<<<dim3(1024), 256, 0, stream>>>(Qws, Kws, Vt, attnw, ctx);

  gemm_out<<<dim3(8, 32), 256, 0, stream>>>(ctx, Wob, bo, x, Yws);

  ln_k<<<dim3(1024), 256, 0, stream>>>(Yws, gamma, beta, out);
}

// Round 7
// 293.829 us; speedup vs baseline: 1.7581x; 1.0355x over previous
//
#include <hip/hip_runtime.h>

typedef __attribute__((ext_vector_type(4))) float f32x4;
typedef __attribute__((ext_vector_type(8))) short bf16x8;
typedef __attribute__((ext_vector_type(4))) short s16x4;
typedef __attribute__((ext_vector_type(4))) unsigned u32x4;
typedef unsigned short u16;

#define GLOAD_LDS16(g, l)                                                      \
  __builtin_amdgcn_global_load_lds(                                            \
      (__attribute__((address_space(1))) const void*)(g),                      \
      (__attribute__((address_space(3))) void*)(l), 16, 0, 0)

static __device__ __forceinline__ u16 f2b(float f) {
  unsigned u = __builtin_bit_cast(unsigned, f);
  unsigned r = (u + 0x7fffu + ((u >> 16) & 1u)) >> 16;
  return (u16)r;
}

// packed f32x2 -> bf16x2 (RNE, matches f2b); no builtin on gfx950
static __device__ __forceinline__ unsigned pk2(float lo, float hi) {
  unsigned r;
  asm("v_cvt_pk_bf16_f32 %0, %1, %2" : "=v"(r) : "v"(lo), "v"(hi));
  return r;
}

static __device__ __forceinline__ f32x4 mfma16(bf16x8 a, bf16x8 b, f32x4 c) {
  return __builtin_amdgcn_mfma_f32_16x16x32_bf16(a, b, c, 0, 0, 0);
}

// bank swizzle: chunk' = chunk ^ fsw(row); fsw spreads the 8 16B-chunks of a
// 128B row across rows so MFMA-fragment reads are 2-way (free) not 16-way.
static __device__ __forceinline__ int fsw(int row) {
  return (row & 7) ^ ((row & 8) >> 1);
}

// ---------------- f32 -> bf16 convert ----------------
__global__ __launch_bounds__(256) void cvt_bf16(const float* __restrict__ in,
                                                u16* __restrict__ out, int n4) {
  int i = blockIdx.x * 256 + threadIdx.x;
  int stride = gridDim.x * 256;
  for (; i < n4; i += stride) {
    float4 v = ((const float4*)in)[i];
    s16x4 o;
    o[0] = (short)f2b(v.x);
    o[1] = (short)f2b(v.y);
    o[2] = (short)f2b(v.z);
    o[3] = (short)f2b(v.w);
    ((s16x4*)out)[i] = o;
  }
}

// 4 weight matrices in one launch (blockIdx.y selects)
__global__ __launch_bounds__(256) void cvt_w4(const float* __restrict__ w0,
                                              const float* __restrict__ w1,
                                              const float* __restrict__ w2,
                                              const float* __restrict__ w3,
                                              u16* __restrict__ o0,
                                              u16* __restrict__ o1,
                                              u16* __restrict__ o2,
                                              u16* __restrict__ o3) {
  int y = blockIdx.y;
  const float* in = (y == 0) ? w0 : (y == 1) ? w1 : (y == 2) ? w2 : w3;
  u16* out = (y == 0) ? o0 : (y == 1) ? o1 : (y == 2) ? o2 : o3;
  const int n4 = 262144;
  int i = blockIdx.x * 256 + threadIdx.x;
  int stride = gridDim.x * 256;
  for (; i < n4; i += stride) {
    float4 v = ((const float4*)in)[i];
    s16x4 o;
    o[0] = (short)f2b(v.x);
    o[1] = (short)f2b(v.y);
    o[2] = (short)f2b(v.z);
    o[3] = (short)f2b(v.w);
    ((s16x4*)out)[i] = o;
  }
}

// ---------------- fused QKV GEMM (z=0:Q scaled, z=1:K, z=2:V transposed) -----
// Q is pre-scaled by log2(e)/sqrt(d_model) so attention uses exp2 directly.
#define QSCALE 0.0450842200278f
__global__ __launch_bounds__(256) void gemm_qkv3(
    const u16* __restrict__ xb, const u16* __restrict__ eb,
    const u16* __restrict__ Wqb, const u16* __restrict__ Wkb,
    const u16* __restrict__ Wvb, const float* __restrict__ bq,
    const float* __restrict__ bk, const float* __restrict__ bv,
    u16* __restrict__ Qd, u16* __restrict__ Kd, u16* __restrict__ Vtd) {
  __shared__ __align__(16) u16 As[128 * 32];
  __shared__ __align__(16) u16 Bs[128 * 32];
  const int K = 1024;
  int z = blockIdx.z;
  const u16* A = (z == 0) ? xb : eb;
  const u16* W = (z == 0) ? Wqb : (z == 1) ? Wkb : Wvb;
  const float* bias = (z == 0) ? bq : (z == 1) ? bk : bv;

  int tid = threadIdx.x;
  int w = tid >> 6, lane = tid & 63;
  int wr = w >> 1, wc = w & 1;
  int r16 = lane & 15, c4 = lane >> 4;
  int m0 = blockIdx.y * 128, n0 = blockIdx.x * 128;
  int srow = tid >> 2;
  int scol = (tid & 3) * 8;

  f32x4 acc[4][4] = {};

  const u16* ga0 = A + (size_t)(m0 + srow) * K + scol;
  const u16* gb0 = W + (size_t)(n0 + srow) * K + scol;
  char* asb = (char*)As + w * 1024;
  char* bsb = (char*)Bs + w * 1024;

  for (int k0 = 0; k0 < K; k0 += 32) {
    GLOAD_LDS16(ga0 + k0, asb);
    GLOAD_LDS16(ga0 + 64 * K + k0, asb + 4096);
    GLOAD_LDS16(gb0 + k0, bsb);
    GLOAD_LDS16(gb0 + 64 * K + k0, bsb + 4096);
    __syncthreads();
    bf16x8 af[4], bfr[4];
#pragma unroll
    for (int i = 0; i < 4; ++i)
      af[i] = *(const bf16x8*)(As + (wr * 64 + i * 16 + r16) * 32 + c4 * 8);
#pragma unroll
    for (int j = 0; j < 4; ++j)
      bfr[j] = *(const bf16x8*)(Bs + (wc * 64 + j * 16 + r16) * 32 + c4 * 8);
#pragma unroll
    for (int i = 0; i < 4; ++i)
#pragma unroll
      for (int j = 0; j < 4; ++j) acc[i][j] = mfma16(af[i], bfr[j], acc[i][j]);
    __syncthreads();
  }

  if (z < 2) {
    float oscale = (z == 0) ? QSCALE : 1.0f;
    u16* dst = (z == 0) ? Qd : Kd;
#pragma unroll
    for (int i = 0; i < 4; ++i) {
      int m = m0 + wr * 64 + i * 16 + c4 * 4;
      int b = m >> 11, s = m & 2047;
#pragma unroll
      for (int j = 0; j < 4; ++j) {
        int n = n0 + wc * 64 + j * 16 + r16;
        int h = n >> 6, d = n & 63;
        float bv = bias[n];
        u16* dp = dst + (((size_t)(b * 16 + h) * 2048 + s) * 64 + d);
#pragma unroll
        for (int r = 0; r < 4; ++r)
          dp[(size_t)r * 64] = f2b((acc[i][j][r] + bv) * oscale);
      }
    }
  } else {
    // V: write transposed, Vt[(bh*64+d)*2048 + s], 4 consecutive s per lane
#pragma unroll
    for (int i = 0; i < 4; ++i) {
      int m = m0 + wr * 64 + i * 16 + c4 * 4;
      int b = m >> 11, s = m & 2047;
#pragma unroll
      for (int j = 0; j < 4; ++j) {
        int n = n0 + wc * 64 + j * 16 + r16;
        int h = n >> 6, d = n & 63;
        float bv = bias[n];
        s16x4 o4;
#pragma unroll
        for (int r = 0; r < 4; ++r) o4[r] = (short)f2b(acc[i][j][r] + bv);
        *(s16x4*)(Vtd + ((size_t)((b * 16 + h) * 64 + d)) * 2048 + s) = o4;
      }
    }
  }
}

// ---------------- out-proj GEMM: Y = ctx * Wo^T + bo + X (f32) ----------------
__global__ __launch_bounds__(256) void gemm_out(const u16* __restrict__ A,
                                                const u16* __restrict__ W,
                                                const float* __restrict__ bias,
                                                const float* __restrict__ X,
                                                float* __restrict__ Y) {
  __shared__ __align__(16) u16 As[128 * 32];
  __shared__ __align__(16) u16 Bs[128 * 32];
  const int K = 1024;
  int tid = threadIdx.x;
  int w = tid >> 6, lane = tid & 63;
  int wr = w >> 1, wc = w & 1;
  int r16 = lane & 15, c4 = lane >> 4;
  int m0 = blockIdx.y * 128, n0 = blockIdx.x * 128;
  int srow = tid >> 2;
  int scol = (tid & 3) * 8;

  f32x4 acc[4][4] = {};

  const u16* ga0 = A + (size_t)(m0 + srow) * K + scol;
  const u16* gb0 = W + (size_t)(n0 + srow) * K + scol;
  char* asb = (char*)As + w * 1024;
  char* bsb = (char*)Bs + w * 1024;

  for (int k0 = 0; k0 < K; k0 += 32) {
    GLOAD_LDS16(ga0 + k0, asb);
    GLOAD_LDS16(ga0 + 64 * K + k0, asb + 4096);
    GLOAD_LDS16(gb0 + k0, bsb);
    GLOAD_LDS16(gb0 + 64 * K + k0, bsb + 4096);
    __syncthreads();
    bf16x8 af[4], bfr[4];
#pragma unroll
    for (int i = 0; i < 4; ++i)
      af[i] = *(const bf16x8*)(As + (wr * 64 + i * 16 + r16) * 32 + c4 * 8);
#pragma unroll
    for (int j = 0; j < 4; ++j)
      bfr[j] = *(const bf16x8*)(Bs + (wc * 64 + j * 16 + r16) * 32 + c4 * 8);
#pragma unroll
    for (int i = 0; i < 4; ++i)
#pragma unroll
      for (int j = 0; j < 4; ++j) acc[i][j] = mfma16(af[i], bfr[j], acc[i][j]);
    __syncthreads();
  }

#pragma unroll
  for (int i = 0; i < 4; ++i) {
    int m = m0 + wr * 64 + i * 16 + c4 * 4;
#pragma unroll
    for (int j = 0; j < 4; ++j) {
      int n = n0 + wc * 64 + j * 16 + r16;
      float bv = bias[n];
#pragma unroll
      for (int r = 0; r < 4; ++r) {
        size_t idx = (size_t)(m + r) * 1024 + n;
        Y[idx] = acc[i][j][r] + bv + X[idx];
      }
    }
  }
}

// ---------------- fused attention v7: counted-vmcnt pipeline -----------------
// Block = 4 waves x 16 q = 64 q; 1024 blocks, 4 blocks/CU. K/V staged via
// global_load_lds, double-buffered. Barrier = s_waitcnt vmcnt(N) + raw
// s_barrier: N = #prefetch loads just issued, so the oldest (the loads)
// retire but the attnw STORES stay in flight across the barrier (no per-step
// store drain). S^T = mfma(K,Q); permuted K-row map -> PV A-frag lane-local.
// Q pre-scaled by log2e/32; normalizer folded into exponent. id%32 = bh ->
// XCD(id%8)=bh%8 keeps each bh's K/V in one XCD L2.
__global__ __launch_bounds__(256, 4) void attn_k(const u16* __restrict__ Q,
                                                 const u16* __restrict__ Kg,
                                                 const u16* __restrict__ Vt,
                                                 float* __restrict__ attnw,
                                                 u16* __restrict__ ctx) {
  __shared__ __align__(16) u16 Klds[2][64 * 64];
  __shared__ __align__(16) u16 Vlds[2][64 * 64];

  int tid = threadIdx.x;
  int w = tid >> 6, lane = tid & 63;
  int r16 = lane & 15, c4 = lane >> 4;
  int id = blockIdx.x;
  int bh = id & 31, qt = id >> 5;
  int b = bh >> 4, h = bh & 15;
  int q0 = qt * 64 + w * 16;

  const u16* Qp = Q + ((size_t)bh * 2048 + q0) * 64;
  const u16* Kp = Kg + (size_t)bh * 2048 * 64;
  const u16* Vp = Vt + (size_t)bh * 64 * 2048;

  bf16x8 qf0 = *(const bf16x8*)(Qp + (size_t)r16 * 64 + c4 * 8);
  bf16x8 qf1 = *(const bf16x8*)(Qp + (size_t)r16 * 64 + 32 + c4 * 8);

  int perm0 = ((r16 >> 2) << 3) + (r16 & 3);
  int srow0 = w * 8 + (lane >> 3);
  int sc = lane & 7;

#define STAGE_K(bufi, kv)                                                      \
  {                                                                            \
    _Pragma("unroll") for (int i = 0; i < 2; ++i) {                            \
      int row = i * 32 + srow0;                                                \
      int ch = sc ^ fsw(row);                                                  \
      GLOAD_LDS16(Kp + (size_t)((kv) + row) * 64 + ch * 8,                     \
                  (u16*)&Klds[bufi][0] + w * 512 + i * 2048);                  \
    }                                                                          \
  }
#define STAGE_V(bufi, kv)                                                      \
  {                                                                            \
    _Pragma("unroll") for (int i = 0; i < 2; ++i) {                            \
      int row = i * 32 + srow0;                                                \
      int ch = sc ^ fsw(row);                                                  \
      GLOAD_LDS16(Vp + (size_t)row * 2048 + (kv) + ch * 8,                     \
                  (u16*)&Vlds[bufi][0] + w * 512 + i * 2048);                  \
    }                                                                          \
  }
#define LDSF(base, row, chunk)                                                 \
  (*(const bf16x8*)((base) + (row) * 64 + (((chunk) ^ fsw(row)) << 3)))
#define WAIT_BAR(n)                                                            \
  {                                                                            \
    asm volatile("s_waitcnt vmcnt(" #n ")" ::: "memory");                      \
    __builtin_amdgcn_s_barrier();                                              \
  }

  // ---------------- pass 1: row sums of exp2(S) ----------------
  float sum = 0.f;
  STAGE_K(0, 0);
  WAIT_BAR(0);
  int buf = 0;
  for (int kv0 = 0; kv0 < 2048; kv0 += 64) {
    if (kv0 + 64 < 2048) STAGE_K(buf ^ 1, kv0 + 64);
    const u16* Kb = &Klds[buf][0];
#pragma unroll
    for (int s = 0; s < 2; ++s) {
      int ra = s * 32 + perm0;
      bf16x8 k00 = LDSF(Kb, ra, c4);
      bf16x8 k01 = LDSF(Kb, ra, c4 + 4);
      bf16x8 k10 = LDSF(Kb, ra + 4, c4);
      bf16x8 k11 = LDSF(Kb, ra + 4, c4 + 4);
      f32x4 s0 = {}, s1 = {};
      __builtin_amdgcn_s_setprio(1);
      s0 = mfma16(k00, qf0, s0);
      s0 = mfma16(k01, qf1, s0);
      s1 = mfma16(k10, qf0, s1);
      s1 = mfma16(k11, qf1, s1);
      __builtin_amdgcn_s_setprio(0);
#pragma unroll
      for (int r = 0; r < 4; ++r)
        sum += __builtin_amdgcn_exp2f(s0[r]) + __builtin_amdgcn_exp2f(s1[r]);
    }
    WAIT_BAR(2);
    buf ^= 1;
  }
  sum += __shfl_xor(sum, 16, 64);
  sum += __shfl_xor(sum, 32, 64);
  float nls = -__log2f(sum);

  // ---------------- pass 2: P write + ctx = P*V ----------------
  f32x4 o[4] = {};
  float* ap = attnw + ((size_t)bh * 2048 + q0 + r16) * 2048;
  STAGE_K(0, 0);
  STAGE_V(0, 0);
  WAIT_BAR(0);
  buf = 0;
  for (int kv0 = 0; kv0 < 2048; kv0 += 64) {
    if (kv0 + 64 < 2048) {
      STAGE_K(buf ^ 1, kv0 + 64);
      STAGE_V(buf ^ 1, kv0 + 64);
    }
    const u16* Kb = &Klds[buf][0];
    const u16* Vb = &Vlds[buf][0];
#pragma unroll
    for (int s = 0; s < 2; ++s) {
      int ra = s * 32 + perm0;
      bf16x8 k00 = LDSF(Kb, ra, c4);
      bf16x8 k01 = LDSF(Kb, ra, c4 + 4);
      bf16x8 k10 = LDSF(Kb, ra + 4, c4);
      bf16x8 k11 = LDSF(Kb, ra + 4, c4 + 4);
      f32x4 s0 = {}, s1 = {};
      __builtin_amdgcn_s_setprio(1);
      s0 = mfma16(k00, qf0, s0);
      s0 = mfma16(k01, qf1, s0);
      s1 = mfma16(k10, qf0, s1);
      s1 = mfma16(k11, qf1, s1);
      __builtin_amdgcn_s_setprio(0);
      f32x4 p0, p1;
#pragma unroll
      for (int r = 0; r < 4; ++r) {
        p0[r] = __builtin_amdgcn_exp2f(s0[r] + nls);
        p1[r] = __builtin_amdgcn_exp2f(s1[r] + nls);
      }
      u32x4 pk;
      pk[0] = pk2(p0[0], p0[1]);
      pk[1] = pk2(p0[2], p0[3]);
      pk[2] = pk2(p1[0], p1[1]);
      pk[3] = pk2(p1[2], p1[3]);
      bf16x8 pf = __builtin_bit_cast(bf16x8, pk);
      bf16x8 v0 = LDSF(Vb, 0 * 16 + r16, s * 4 + c4);
      bf16x8 v1 = LDSF(Vb, 1 * 16 + r16, s * 4 + c4);
      bf16x8 v2 = LDSF(Vb, 2 * 16 + r16, s * 4 + c4);
      bf16x8 v3 = LDSF(Vb, 3 * 16 + r16, s * 4 + c4);
      __builtin_amdgcn_s_setprio(1);
      o[0] = mfma16(pf, v0, o[0]);
      o[1] = mfma16(pf, v1, o[1]);
      o[2] = mfma16(pf, v2, o[2]);
      o[3] = mfma16(pf, v3, o[3]);
      __builtin_amdgcn_s_setprio(0);
      int kvc = kv0 + s * 32 + c4 * 8;
      *(f32x4*)(ap + kvc) = p0;
      *(f32x4*)(ap + kvc + 4) = p1;
    }
    WAIT_BAR(4);
    buf ^= 1;
  }

#pragma unroll
  for (int dt = 0; dt < 4; ++dt)
#pragma unroll
    for (int r = 0; r < 4; ++r)
      ctx[((size_t)(b * 2048 + q0 + c4 * 4 + r)) * 1024 + h * 64 + dt * 16 +
          r16] = f2b(o[dt][r]);
#undef STAGE_K
#undef STAGE_V
#undef LDSF
#undef WAIT_BAR
}

// ---------------- LayerNorm over last dim (1024), wave per row ----------------
__global__ __launch_bounds__(256) void ln_k(const float* __restrict__ Y,
                                            const float* __restrict__ gamma,
                                            const float* __restrict__ beta,
                                            float* __restrict__ out) {
  int row = blockIdx.x * 4 + (threadIdx.x >> 6);
  int lane = threadIdx.x & 63;
  const float* yr = Y + (size_t)row * 1024;
  float4 v[4];
  float sum = 0.f, sq = 0.f;
#pragma unroll
  for (int i = 0; i < 4; ++i) {
    v[i] = *(const float4*)(yr + i * 256 + lane * 4);
    sum += v[i].x + v[i].y + v[i].z + v[i].w;
    sq += v[i].x * v[i].x + v[i].y * v[i].y + v[i].z * v[i].z + v[i].w * v[i].w;
  }
#pragma unroll
  for (int m = 1; m < 64; m <<= 1) {
    sum += __shfl_xor(sum, m, 64);
    sq += __shfl_xor(sq, m, 64);
  }
  float mu = sum * (1.f / 1024.f);
  float var = sq * (1.f / 1024.f) - mu * mu;
  float rs = rsqrtf(var + 1e-5f);
  float* orow = out + (size_t)row * 1024;
#pragma unroll
  for (int i = 0; i < 4; ++i) {
    int c = i * 256 + lane * 4;
    float4 g = *(const float4*)(gamma + c);
    float4 be = *(const float4*)(beta + c);
    float4 o;
    o.x = (v[i].x - mu) * rs * g.x + be.x;
    o.y = (v[i].y - mu) * rs * g.y + be.y;
    o.z = (v[i].z - mu) * rs * g.z + be.z;
    o.w = (v[i].w - mu) * rs * g.w + be.w;
    *(float4*)(orow + c) = o;
  }
}

extern "C" void kernel_launch(void* const* d_in, const int* in_sizes, int n_in,
                              void* d_out, int out_size, void* d_ws,
                              size_t ws_size, hipStream_t stream) {
  const float* x = (const float*)d_in[0];
  const float* enc = (const float*)d_in[1];
  const float* Wq = (const float*)d_in[2];
  const float* bq = (const float*)d_in[3];
  const float* Wk = (const float*)d_in[4];
  const float* bk = (const float*)d_in[5];
  const float* Wv = (const float*)d_in[6];
  const float* bv = (const float*)d_in[7];
  const float* Wo = (const float*)d_in[8];
  const float* bo = (const float*)d_in[9];
  const float* gamma = (const float*)d_in[10];
  const float* beta = (const float*)d_in[11];

  float* out = (float*)d_out;
  float* attnw = out + (size_t)4194304;  // 2*2048*1024

  char* ws = (char*)d_ws;
  u16* xb = (u16*)(ws + (size_t)0);
  u16* eb = (u16*)(ws + ((size_t)8 << 20));
  u16* Wqb = (u16*)(ws + ((size_t)16 << 20));
  u16* Wkb = (u16*)(ws + ((size_t)18 << 20));
  u16* Wvb = (u16*)(ws + ((size_t)20 << 20));
  u16* Wob = (u16*)(ws + ((size_t)22 << 20));
  u16* Qws = (u16*)(ws + ((size_t)24 << 20));
  u16* Kws = (u16*)(ws + ((size_t)32 << 20));
  u16* Vt = (u16*)(ws + ((size_t)48 << 20));
  u16* ctx = (u16*)(ws + ((size_t)40 << 20));
  float* Yws = (float*)(ws + (size_t)0);  // reuse xb/eb (dead after gemms)

  cvt_bf16<<<dim3(1024), 256, 0, stream>>>(x, xb, 1048576);
  cvt_bf16<<<dim3(1024), 256, 0, stream>>>(enc, eb, 1048576);
  cvt_w4<<<dim3(256, 4), 256, 0, stream>>>(Wq, Wk, Wv, Wo, Wqb, Wkb, Wvb, Wob);

  gemm_qkv3<<<dim3(8, 32, 3), 256, 0, stream>>>(xb, eb, Wqb, Wkb, Wvb, bq, bk,
                                                bv, Qws, Kws, Vt);

  attn_k<<<dim3(1024), 256, 0, stream>>>(Qws, Kws, Vt, attnw, ctx);

  gemm_out<<<dim3(8, 32), 256, 0, stream>>>(ctx, Wob, bo, x, Yws);

  ln_k<<<dim3(1024), 256, 0, stream>>>(Yws, gamma, beta, out);
}